// Round 4
// baseline (327.014 us; speedup 1.0000x reference)
//
#include <hip/hip_runtime.h>
#include <hip/hip_bf16.h>

// ---------------------------------------------------------------------------
// FFT butterfly attention. delta = x_a^T P (x_a - x_b), P = scale*Wq*Wk^T
// (bf16, MFMA prep). w0 = sigmoid(delta); v' = mix(va, vb).
//
// Round-4 structure: transposed GEMM Gt = P^T @ Xa^T (round-1, harness-
// verified) fed by COALESCED fragment-major PTf A-frags (round-3 layout is
// bit-identical to what the transposed A-frags need: frag (c>>4,kk) at
// uint4 Pf[(ci*4+kk)*64+lane]). Wave w (nt=w&3 pair-tile, mh=w>>2 k-half)
// holds Gt[c][p] in acc registers; the delta dot is IN-WAVE (16 FMAs vs
// dx from xb, xor16+xor32 reduce, one scalar wt write per half).
//  -> NO gbuf (LDS 51.9K -> 35.8K), ONE barrier/stage (wt double-buffered),
//  -> launch_bounds(512,8): VGPR cap 64 -> 4 blocks/CU; grid 1024 = exactly
//     one dispatch round across 256 CUs (no tail).
// A-frag addresses are wave-uniform base + lane*16B: 1 VGPR, pure coalesced
// L2 streams (fixes round-1's 16-segment-gather stall).
//
// v register layout (pair-local): at stage u, lane L holds BOTH partners:
//   vlo = row ((L>>u)<<(u+1)) | (L & (2^u-1)),  vhi = vlo + 2^u
// -> mix is pure in-thread VALU; between stages each lane exchanges one value
// with lane L^2^u (DPP quad_perm / ds_swizzle xor / ds_bpermute), fused in.
// ---------------------------------------------------------------------------

typedef __bf16 bf16x8 __attribute__((ext_vector_type(8)));
typedef float  f32x4  __attribute__((ext_vector_type(4)));

#define XSTR 136                    // bf16 elems per xb row (128 + 8 pad; 272B rows)
#define XB_BYTES  (128 * XSTR * 2)  // 34816
#define WT_OFF    XB_BYTES
#define LDS_MAIN  (WT_OFF + 2 * 128 * 4)  // 35840 -> 4 WGs/CU (LDS)
#define PREP_LDS  (2 * XB_BYTES)    // 69632

__device__ __forceinline__ float ubits(unsigned int u) {
    union { unsigned int u; float f; } v; v.u = u; return v.f;
}
__device__ __forceinline__ unsigned short f2bf(float f) {
    union { float f; unsigned int u; } v; v.f = f;
    unsigned int u = v.u;
    return (unsigned short)((u + 0x7fffu + ((u >> 16) & 1u)) >> 16);
}

#define DPP_MOV_F(x, ctrl) \
    __int_as_float(__builtin_amdgcn_update_dpp(0, __float_as_int(x), (ctrl), 0xF, 0xF, true))

// cross-lane xor exchange with lane ^ (1<<u); u is compile-time-folded
__device__ __forceinline__ float xlane_u(float x, int u, int lane) {
    if (u == 0) return DPP_MOV_F(x, 0xB1);   // quad_perm xor1
    if (u == 1) return DPP_MOV_F(x, 0x4E);   // quad_perm xor2
    if (u == 2) return __int_as_float(__builtin_amdgcn_ds_swizzle(__float_as_int(x), 0x101F)); // xor4
    if (u == 3) return __int_as_float(__builtin_amdgcn_ds_swizzle(__float_as_int(x), 0x201F)); // xor8
    if (u == 4) return __int_as_float(__builtin_amdgcn_ds_swizzle(__float_as_int(x), 0x401F)); // xor16
    return __int_as_float(__builtin_amdgcn_ds_bpermute((lane ^ 32) << 2, __float_as_int(x))); // xor32
}

// ---------------- prep: PTf = fragment-major P^T -----------------------------
// Element (n,k) of PT (n = P^T row, k = contraction dim) lives at
//   fi = ((n>>4)*4 + (k>>5))*64 + lane, elem k&7   with lane = quad'*16+l15'
// so any 16-row tile ci's frag (ci,kk) = Pf[(ci*4+kk)*64 + lane]: 1KB coalesced.
__global__ __launch_bounds__(512)
void prep_kernel(const float* __restrict__ qkw, unsigned short* __restrict__ PT) {
    extern __shared__ char smem[];
    unsigned short* wkb = (unsigned short*)smem;              // A: Wk rows (n)
    unsigned short* wqb = (unsigned short*)(smem + XB_BYTES); // B: Wq rows (k)
    const int s = blockIdx.x;
    const float* Wq = qkw + (size_t)s * 32768;
    const float* Wk = Wq + 16384;
    const int tid = threadIdx.x;
    const int rl = tid >> 5, c4 = tid & 31;
#pragma unroll
    for (int j = 0; j < 8; ++j) {
        int r = j * 16 + rl;
        float4 vq = ((const float4*)Wq)[r * 32 + c4];
        float4 vk = ((const float4*)Wk)[r * 32 + c4];
        ushort4 uq; uq.x = f2bf(vq.x); uq.y = f2bf(vq.y); uq.z = f2bf(vq.z); uq.w = f2bf(vq.w);
        ushort4 uk; uk.x = f2bf(vk.x); uk.y = f2bf(vk.y); uk.z = f2bf(vk.z); uk.w = f2bf(vk.w);
        *(ushort4*)(wqb + r * XSTR + c4 * 4) = uq;
        *(ushort4*)(wkb + r * XSTR + c4 * 4) = uk;
    }
    __syncthreads();
    const int lane = tid & 63, w = tid >> 6;
    const int lane15 = lane & 15, quad = lane >> 4;
    f32x4 acc[8] = {};
#pragma unroll
    for (int kk = 0; kk < 4; ++kk) {
        bf16x8 a = *(const bf16x8*)(wkb + (w * 16 + lane15) * XSTR + kk * 32 + quad * 8);
#pragma unroll
        for (int ct = 0; ct < 8; ++ct) {
            bf16x8 b = *(const bf16x8*)(wqb + (ct * 16 + lane15) * XSTR + kk * 32 + quad * 8);
            acc[ct] = __builtin_amdgcn_mfma_f32_16x16x32_bf16(a, b, acc[ct], 0, 0, 0);
        }
    }
    // acc[ct][r] = PT[n][k], n = w*16 + quad*4 + r, k = ct*16 + lane15
    unsigned short* dst = PT + s * 16384;
#pragma unroll
    for (int ct = 0; ct < 8; ++ct) {
        const int kkf = ct >> 1;
        const int qf  = (ct & 1) * 2 + (lane15 >> 3);
        const int e   = lane15 & 7;
#pragma unroll
        for (int r = 0; r < 4; ++r) {
            int fi = (w * 4 + kkf) * 64 + qf * 16 + quad * 4 + r;
            dst[fi * 8 + e] = f2bf(acc[ct][r] * 0.17677669529663687f);
        }
    }
}

// ---------------- fused butterfly stages ------------------------------------
template<int NS>
__global__ __launch_bounds__(512, 8)
void butterfly_kernel(const float* __restrict__ xsrc,
                      const float* __restrict__ vsrc,
                      float* __restrict__ vdst,
                      const unsigned short* __restrict__ PT,
                      int s0, int base_mul, int h_off, int rstride)
{
    extern __shared__ char smem[];
    unsigned short* xb = (unsigned short*)smem;
    float*          wt = (float*)(smem + WT_OFF);   // [2][128] double-buffered

    const int tid  = threadIdx.x;
    const int b    = blockIdx.x >> 6;
    const int sub  = blockIdx.x & 63;
    const int base = b * 8192 + sub * base_mul;

    // ---- stage x -> xb (bf16), coalesced ----
    {
        const int rl = tid >> 5, c4 = tid & 31;
#pragma unroll
        for (int j = 0; j < 8; ++j) {
            int i  = j * 16 + rl;
            int gp = base + (i >> 6) * h_off + (i & 63) * rstride;
            float4 val = ((const float4*)xsrc)[gp * 32 + c4];
            ushort4 us; us.x = f2bf(val.x); us.y = f2bf(val.y);
            us.z = f2bf(val.z); us.w = f2bf(val.w);
            *(ushort4*)(xb + i * XSTR + c4 * 4) = us;
        }
    }

    const int lane = tid & 63, w = tid >> 6;
    const int lane15 = lane & 15, quad = lane >> 4;
    const int nt = w & 3;              // pair tile: pairs nt*16..nt*16+15
    const int mh = w >> 2;             // k-half: dims mh*64..mh*64+63
    const int p  = nt * 16 + lane15;   // this lane's pair

    // ---- v into registers, pair-local for stage 0: rows (2L, 2L+1) ----
    float vlo[16], vhi[16];
    {
        int r0 = 2 * lane, r1 = r0 + 1;
        int gp0 = base + (r0 >> 6) * h_off + (r0 & 63) * rstride;
        int gp1 = base + (r1 >> 6) * h_off + (r1 & 63) * rstride;
        const float* p0 = vsrc + (size_t)gp0 * 128 + w * 16;
        const float* p1 = vsrc + (size_t)gp1 * 128 + w * 16;
#pragma unroll
        for (int j = 0; j < 4; ++j) {
            float4 a = ((const float4*)p0)[j];
            float4 c = ((const float4*)p1)[j];
            vlo[4*j] = a.x; vlo[4*j+1] = a.y; vlo[4*j+2] = a.z; vlo[4*j+3] = a.w;
            vhi[4*j] = c.x; vhi[4*j+1] = c.y; vhi[4*j+2] = c.z; vhi[4*j+3] = c.w;
        }
    }
    __syncthreads();   // xb ready

#pragma unroll
    for (int u = 0; u < NS; ++u) {
        const int t   = 1 << u;
        const int tm1 = t - 1;
        const int ar  = ((p & ~tm1) << 1) | (p & tm1);   // xb row of pair p's 'a'

        // ---- Gt = P^T @ Xa^T : wave-local 16x(4x16) tile, acc in registers.
        // A-frag: PTf frag (mh*4+mt, kk), wave-uniform base + lane*16B.
        // B-frag: xb row ar(p), k contiguous.
        // C: col(lane15)=pair, row(quad*4+r)=c  -> dot is in-wave.
        float sm = 0.f;
        {
            const uint4* Pf = (const uint4*)PT + (size_t)(s0 + u) * 2048;
            const unsigned short* brow = xb + ar * XSTR + quad * 8;
            f32x4 acc[4] = {};
#pragma unroll
            for (int kk = 0; kk < 4; ++kk) {
                bf16x8 bfrag = *(const bf16x8*)(brow + kk * 32);
#pragma unroll
                for (int mt = 0; mt < 4; ++mt) {
                    union { uint4 u; bf16x8 b; } av;
                    av.u = Pf[((mh * 4 + mt) * 4 + kk) * 64 + lane];
                    acc[mt] = __builtin_amdgcn_mfma_f32_16x16x32_bf16(av.b, bfrag, acc[mt], 0, 0, 0);
                }
            }
            // ---- in-register partial dot: sum_c Gt[c][p] * (xa[p][c]-xb[p][c])
            const unsigned short* da = xb + ar * XSTR + mh * 64 + quad * 4;
            const unsigned short* db = da + t * XSTR;
#pragma unroll
            for (int mt = 0; mt < 4; ++mt) {
                uint2 ua = *(const uint2*)(da + mt * 16);
                uint2 ub = *(const uint2*)(db + mt * 16);
                float a0 = ubits(ua.x << 16), a1 = ubits(ua.x & 0xffff0000u);
                float a2 = ubits(ua.y << 16), a3 = ubits(ua.y & 0xffff0000u);
                float b0 = ubits(ub.x << 16), b1 = ubits(ub.x & 0xffff0000u);
                float b2 = ubits(ub.y << 16), b3 = ubits(ub.y & 0xffff0000u);
                sm += acc[mt][0] * (a0 - b0) + acc[mt][1] * (a1 - b1)
                    + acc[mt][2] * (a2 - b2) + acc[mt][3] * (a3 - b3);
            }
        }
        // reduce over quads (lanes ^16, ^32 share lane15/pair)
        sm += xlane_u(sm, 4, lane);
        sm += xlane_u(sm, 5, lane);
        if (lane < 16) wt[(u & 1) * 128 + mh * 64 + nt * 16 + lane] = sm;
        __syncthreads();   // wt ready (single barrier per stage; wt dbuf'd)

        // ---- mix (in-thread) + fused pair exchange for next stage ----
        {
            const float d  = wt[(u & 1) * 128 + lane] + wt[(u & 1) * 128 + 64 + lane];
            const float w0 = 1.0f / (1.0f + __expf(-d));
            if (u < NS - 1) {
                const bool isE = ((lane >> u) & 1) == 0;
                const float wk = isE ? w0 : 1.0f - w0;
#pragma unroll
                for (int j = 0; j < 16; ++j) {
                    float a = vlo[j], c = vhi[j];
                    float s    = a + c;
                    float keep = c + wk * (a - c);   // E: out_a ; O: out_b
                    float send = s - keep;           // E: out_b ; O: out_a
                    float ex   = xlane_u(send, u, lane);
                    vlo[j] = isE ? keep : ex;
                    vhi[j] = isE ? ex : keep;
                }
            } else {
                const float w1 = 1.0f - w0;
#pragma unroll
                for (int j = 0; j < 16; ++j) {
                    float a = vlo[j], c = vhi[j];
                    float oa = w0 * a + w1 * c;
                    vlo[j] = oa;
                    vhi[j] = a + c - oa;
                }
            }
        }
    }

    // ---- store v registers -> vdst (layout of final stage NS-1) ----
    {
        const int FU = NS - 1;
        int r0 = ((lane >> FU) << (FU + 1)) | (lane & ((1 << FU) - 1));
        int r1 = r0 + (1 << FU);
        int gp0 = base + (r0 >> 6) * h_off + (r0 & 63) * rstride;
        int gp1 = base + (r1 >> 6) * h_off + (r1 & 63) * rstride;
        float* p0 = vdst + (size_t)gp0 * 128 + w * 16;
        float* p1 = vdst + (size_t)gp1 * 128 + w * 16;
#pragma unroll
        for (int j = 0; j < 4; ++j) {
            float4 a; a.x = vlo[4*j]; a.y = vlo[4*j+1]; a.z = vlo[4*j+2]; a.w = vlo[4*j+3];
            float4 c; c.x = vhi[4*j]; c.y = vhi[4*j+1]; c.z = vhi[4*j+2]; c.w = vhi[4*j+3];
            ((float4*)p0)[j] = a;
            ((float4*)p1)[j] = c;
        }
    }
}

extern "C" void kernel_launch(void* const* d_in, const int* in_sizes, int n_in,
                              void* d_out, int out_size, void* d_ws, size_t ws_size,
                              hipStream_t stream) {
    const float* x   = (const float*)d_in[0];
    const float* qkw = (const float*)d_in[1];
    float* out = (float*)d_out;
    unsigned short* PT = (unsigned short*)d_ws;   // 13*16384 bf16 = 416 KB

    (void)hipFuncSetAttribute((const void*)prep_kernel,
                              hipFuncAttributeMaxDynamicSharedMemorySize, PREP_LDS);
    (void)hipFuncSetAttribute((const void*)butterfly_kernel<7>,
                              hipFuncAttributeMaxDynamicSharedMemorySize, LDS_MAIN);
    (void)hipFuncSetAttribute((const void*)butterfly_kernel<6>,
                              hipFuncAttributeMaxDynamicSharedMemorySize, LDS_MAIN);

    prep_kernel<<<13, 512, PREP_LDS, stream>>>(qkw, PT);

    // stages 0..6: contiguous 128-position blocks; v init = x
    butterfly_kernel<7><<<1024, 512, LDS_MAIN, stream>>>(
        x, x, out, PT, /*s0=*/0, /*base_mul=*/128, /*h_off=*/64, /*rstride=*/1);

    // stages 7..12: 2 lo x 64 hi (stride 128); in-place on d_out
    butterfly_kernel<6><<<1024, 512, LDS_MAIN, stream>>>(
        x, out, out, PT, /*s0=*/7, /*base_mul=*/2, /*h_off=*/1, /*rstride=*/128);
}

// Round 5
// 243.639 us; speedup vs baseline: 1.3422x; 1.3422x over previous
//
#include <hip/hip_runtime.h>
#include <hip/hip_bf16.h>

// ---------------------------------------------------------------------------
// FFT butterfly attention. delta = x_a^T P (x_a - x_b), P = scale*Wq*Wk^T
// (bf16, MFMA prep). w0 = sigmoid(delta); v' = mix(va, vb).
//
// KEY STRUCTURAL FACT: weights depend ONLY on x and PT, never on v. So:
//  * weights_kernel: transposed GEMM Gt = P^T @ Xa^T (round-4 dataflow,
//    harness-verified numerics) + in-wave dot + xor16/32 reduce. NO v state
//    -> ~70 live VGPRs, no spill at cap 128. ZERO barriers in the stage loop
//    (half-sums stored straight to global dwt; sigmoid deferred to mix).
//    LDS = xb only (34.8K) -> 4 blocks/CU.
//  * mix_kernel: register-resident v chain (verified). No MFMA, no LDS,
//    NO barriers at all: per stage read 2 weight halves from dwt, sigmoid,
//    in-thread mix + DPP/swizzle pair exchange. Pure streaming.
// dwt = 13*1024*128 f32 = 6.8 MB in d_ws (after PT). If ws_size is too
// small, fall back to the verified round-3 fused kernel (248.8us).
//
// v register layout (pair-local): at stage u, lane L holds BOTH partners:
//   vlo = row ((L>>u)<<(u+1)) | (L & (2^u-1)),  vhi = vlo + 2^u
// (pair index of lane L == L; exchange partner lane L^2^u.)
// ---------------------------------------------------------------------------

typedef __bf16 bf16x8 __attribute__((ext_vector_type(8)));
typedef float  f32x4  __attribute__((ext_vector_type(4)));

#define XSTR 136                    // bf16 elems per xb row (128 + 8 pad)
#define XB_BYTES  (128 * XSTR * 2)  // 34816
#define PREP_LDS  (2 * XB_BYTES)    // 69632
#define LDS_W     XB_BYTES          // weights kernel: xb only

// fused-fallback LDS layout (round-3, verified)
#define GH_STR 132
#define GB_OFF    XB_BYTES
#define GB_BYTES  (64 * GH_STR * 2) // 16896
#define WT_OFF_F  (GB_OFF + GB_BYTES)
#define LDS_FUSED (WT_OFF_F + 64 * 4) // 51968

// workspace layout
#define WS_DWT_OFF (512 * 1024)                      // PT in [0, 416K)
#define WS_NEED    (WS_DWT_OFF + 13 * 1024 * 128 * 4) // + 6.8 MB dwt

__device__ __forceinline__ float ubits(unsigned int u) {
    union { unsigned int u; float f; } v; v.u = u; return v.f;
}
__device__ __forceinline__ unsigned short f2bf(float f) {
    union { float f; unsigned int u; } v; v.f = f;
    unsigned int u = v.u;
    return (unsigned short)((u + 0x7fffu + ((u >> 16) & 1u)) >> 16);
}

#define DPP_MOV_F(x, ctrl) \
    __int_as_float(__builtin_amdgcn_update_dpp(0, __float_as_int(x), (ctrl), 0xF, 0xF, true))
#define DPP_ADD_F(s, ctrl) s += DPP_MOV_F(s, ctrl)

// cross-lane xor exchange with lane ^ (1<<u); u is compile-time-folded
__device__ __forceinline__ float xlane_u(float x, int u, int lane) {
    if (u == 0) return DPP_MOV_F(x, 0xB1);   // quad_perm xor1
    if (u == 1) return DPP_MOV_F(x, 0x4E);   // quad_perm xor2
    if (u == 2) return __int_as_float(__builtin_amdgcn_ds_swizzle(__float_as_int(x), 0x101F)); // xor4
    if (u == 3) return __int_as_float(__builtin_amdgcn_ds_swizzle(__float_as_int(x), 0x201F)); // xor8
    if (u == 4) return __int_as_float(__builtin_amdgcn_ds_swizzle(__float_as_int(x), 0x401F)); // xor16
    return __int_as_float(__builtin_amdgcn_ds_bpermute((lane ^ 32) << 2, __float_as_int(x))); // xor32
}

// ---------------- prep: PTf = fragment-major P^T -----------------------------
// frag (ci,kk) of any 16-row tile ci at uint4 Pf[(ci*4+kk)*64 + lane]: 1KB coalesced.
__global__ __launch_bounds__(512)
void prep_kernel(const float* __restrict__ qkw, unsigned short* __restrict__ PT) {
    extern __shared__ char smem[];
    unsigned short* wkb = (unsigned short*)smem;              // A: Wk rows (n)
    unsigned short* wqb = (unsigned short*)(smem + XB_BYTES); // B: Wq rows (k)
    const int s = blockIdx.x;
    const float* Wq = qkw + (size_t)s * 32768;
    const float* Wk = Wq + 16384;
    const int tid = threadIdx.x;
    const int rl = tid >> 5, c4 = tid & 31;
#pragma unroll
    for (int j = 0; j < 8; ++j) {
        int r = j * 16 + rl;
        float4 vq = ((const float4*)Wq)[r * 32 + c4];
        float4 vk = ((const float4*)Wk)[r * 32 + c4];
        ushort4 uq; uq.x = f2bf(vq.x); uq.y = f2bf(vq.y); uq.z = f2bf(vq.z); uq.w = f2bf(vq.w);
        ushort4 uk; uk.x = f2bf(vk.x); uk.y = f2bf(vk.y); uk.z = f2bf(vk.z); uk.w = f2bf(vk.w);
        *(ushort4*)(wqb + r * XSTR + c4 * 4) = uq;
        *(ushort4*)(wkb + r * XSTR + c4 * 4) = uk;
    }
    __syncthreads();
    const int lane = tid & 63, w = tid >> 6;
    const int lane15 = lane & 15, quad = lane >> 4;
    f32x4 acc[8] = {};
#pragma unroll
    for (int kk = 0; kk < 4; ++kk) {
        bf16x8 a = *(const bf16x8*)(wkb + (w * 16 + lane15) * XSTR + kk * 32 + quad * 8);
#pragma unroll
        for (int ct = 0; ct < 8; ++ct) {
            bf16x8 b = *(const bf16x8*)(wqb + (ct * 16 + lane15) * XSTR + kk * 32 + quad * 8);
            acc[ct] = __builtin_amdgcn_mfma_f32_16x16x32_bf16(a, b, acc[ct], 0, 0, 0);
        }
    }
    // acc[ct][r] = PT[n][k], n = w*16 + quad*4 + r, k = ct*16 + lane15
    unsigned short* dst = PT + s * 16384;
#pragma unroll
    for (int ct = 0; ct < 8; ++ct) {
        const int kkf = ct >> 1;
        const int qf  = (ct & 1) * 2 + (lane15 >> 3);
        const int e   = lane15 & 7;
#pragma unroll
        for (int r = 0; r < 4; ++r) {
            int fi = (w * 4 + kkf) * 64 + qf * 16 + quad * 4 + r;
            dst[fi * 8 + e] = f2bf(acc[ct][r] * 0.17677669529663687f);
        }
    }
}

// ---------------- weights kernel: dwt halves, barrier-free stage loop --------
template<int NS>
__global__ __launch_bounds__(512, 4)
void weights_kernel(const float* __restrict__ xsrc,
                    const unsigned short* __restrict__ PT,
                    float* __restrict__ dwt,
                    int s0, int base_mul, int h_off, int rstride)
{
    extern __shared__ char smem[];
    unsigned short* xb = (unsigned short*)smem;

    const int tid  = threadIdx.x;
    const int b    = blockIdx.x >> 6;
    const int sub  = blockIdx.x & 63;
    const int base = b * 8192 + sub * base_mul;

    // ---- stage x -> xb (bf16), coalesced ----
    {
        const int rl = tid >> 5, c4 = tid & 31;
#pragma unroll
        for (int j = 0; j < 8; ++j) {
            int i  = j * 16 + rl;
            int gp = base + (i >> 6) * h_off + (i & 63) * rstride;
            float4 val = ((const float4*)xsrc)[gp * 32 + c4];
            ushort4 us; us.x = f2bf(val.x); us.y = f2bf(val.y);
            us.z = f2bf(val.z); us.w = f2bf(val.w);
            *(ushort4*)(xb + i * XSTR + c4 * 4) = us;
        }
    }

    const int lane = tid & 63, w = tid >> 6;
    const int lane15 = lane & 15, quad = lane >> 4;
    const int nt = w & 3;              // pair tile: pairs nt*16..nt*16+15
    const int mh = w >> 2;             // k-half: dims mh*64..mh*64+63
    const int p  = nt * 16 + lane15;   // this lane's pair

    __syncthreads();   // xb ready; NO further barriers (xb read-only below)

#pragma unroll
    for (int u = 0; u < NS; ++u) {
        const int t   = 1 << u;
        const int tm1 = t - 1;
        const int ar  = ((p & ~tm1) << 1) | (p & tm1);   // xb row of pair p's 'a'

        // ---- Gt = P^T @ Xa^T, wave-local; acc consumed in-register ----
        float sm = 0.f;
        {
            const uint4* Pf = (const uint4*)PT + (size_t)(s0 + u) * 2048;
            const unsigned short* brow = xb + ar * XSTR + quad * 8;
            f32x4 acc[4] = {};
#pragma unroll
            for (int kk = 0; kk < 4; ++kk) {
                bf16x8 bfrag = *(const bf16x8*)(brow + kk * 32);
#pragma unroll
                for (int mt = 0; mt < 4; ++mt) {
                    union { uint4 u; bf16x8 b; } av;
                    av.u = Pf[((mh * 4 + mt) * 4 + kk) * 64 + lane];
                    acc[mt] = __builtin_amdgcn_mfma_f32_16x16x32_bf16(av.b, bfrag, acc[mt], 0, 0, 0);
                }
            }
            // in-register partial dot: sum_c Gt[c][p] * (xa[p][c]-xb[p][c])
            const unsigned short* da = xb + ar * XSTR + mh * 64 + quad * 4;
            const unsigned short* db = da + t * XSTR;
#pragma unroll
            for (int mt = 0; mt < 4; ++mt) {
                uint2 ua = *(const uint2*)(da + mt * 16);
                uint2 ub = *(const uint2*)(db + mt * 16);
                float a0 = ubits(ua.x << 16), a1 = ubits(ua.x & 0xffff0000u);
                float a2 = ubits(ua.y << 16), a3 = ubits(ua.y & 0xffff0000u);
                float b0 = ubits(ub.x << 16), b1 = ubits(ub.x & 0xffff0000u);
                float b2 = ubits(ub.y << 16), b3 = ubits(ub.y & 0xffff0000u);
                sm += acc[mt][0] * (a0 - b0) + acc[mt][1] * (a1 - b1)
                    + acc[mt][2] * (a2 - b2) + acc[mt][3] * (a3 - b3);
            }
        }
        // reduce over quads (lanes ^16, ^32 share pair p)
        sm += xlane_u(sm, 4, lane);
        sm += xlane_u(sm, 5, lane);
        if (lane < 16)
            dwt[((size_t)(s0 + u) * 1024 + blockIdx.x) * 128 + mh * 64 + nt * 16 + lane] = sm;
    }
}

// ---------------- mix kernel: no LDS, no barriers, pure streaming ------------
template<int NS>
__global__ __launch_bounds__(512, 4)
void mix_kernel(const float* __restrict__ vsrc,
                float* __restrict__ vdst,
                const float* __restrict__ dwt,
                int s0, int base_mul, int h_off, int rstride)
{
    const int tid  = threadIdx.x;
    const int b    = blockIdx.x >> 6;
    const int sub  = blockIdx.x & 63;
    const int base = b * 8192 + sub * base_mul;
    const int lane = tid & 63, w = tid >> 6;

    // ---- v into registers, pair-local for stage 0: rows (2L, 2L+1) ----
    float vlo[16], vhi[16];
    {
        int r0 = 2 * lane, r1 = r0 + 1;
        int gp0 = base + (r0 >> 6) * h_off + (r0 & 63) * rstride;
        int gp1 = base + (r1 >> 6) * h_off + (r1 & 63) * rstride;
        const float* p0 = vsrc + (size_t)gp0 * 128 + w * 16;
        const float* p1 = vsrc + (size_t)gp1 * 128 + w * 16;
#pragma unroll
        for (int j = 0; j < 4; ++j) {
            float4 a = ((const float4*)p0)[j];
            float4 c = ((const float4*)p1)[j];
            vlo[4*j] = a.x; vlo[4*j+1] = a.y; vlo[4*j+2] = a.z; vlo[4*j+3] = a.w;
            vhi[4*j] = c.x; vhi[4*j+1] = c.y; vhi[4*j+2] = c.z; vhi[4*j+3] = c.w;
        }
    }

#pragma unroll
    for (int u = 0; u < NS; ++u) {
        const float* dw = dwt + ((size_t)(s0 + u) * 1024 + blockIdx.x) * 128;
        const float d  = dw[lane] + dw[64 + lane];   // two half-sums
        const float w0 = 1.0f / (1.0f + __expf(-d));
        if (u < NS - 1) {
            const bool isE = ((lane >> u) & 1) == 0;
            const float wk = isE ? w0 : 1.0f - w0;
#pragma unroll
            for (int j = 0; j < 16; ++j) {
                float a = vlo[j], c = vhi[j];
                float s    = a + c;
                float keep = c + wk * (a - c);   // E: out_a ; O: out_b
                float send = s - keep;           // E: out_b ; O: out_a
                float ex   = xlane_u(send, u, lane);
                vlo[j] = isE ? keep : ex;
                vhi[j] = isE ? ex : keep;
            }
        } else {
            const float w1 = 1.0f - w0;
#pragma unroll
            for (int j = 0; j < 16; ++j) {
                float a = vlo[j], c = vhi[j];
                float oa = w0 * a + w1 * c;
                vlo[j] = oa;
                vhi[j] = a + c - oa;
            }
        }
    }

    // ---- store v registers -> vdst (layout of final stage NS-1) ----
    {
        const int FU = NS - 1;
        int r0 = ((lane >> FU) << (FU + 1)) | (lane & ((1 << FU) - 1));
        int r1 = r0 + (1 << FU);
        int gp0 = base + (r0 >> 6) * h_off + (r0 & 63) * rstride;
        int gp1 = base + (r1 >> 6) * h_off + (r1 & 63) * rstride;
        float* p0 = vdst + (size_t)gp0 * 128 + w * 16;
        float* p1 = vdst + (size_t)gp1 * 128 + w * 16;
#pragma unroll
        for (int j = 0; j < 4; ++j) {
            float4 a; a.x = vlo[4*j]; a.y = vlo[4*j+1]; a.z = vlo[4*j+2]; a.w = vlo[4*j+3];
            float4 c; c.x = vhi[4*j]; c.y = vhi[4*j+1]; c.z = vhi[4*j+2]; c.w = vhi[4*j+3];
            ((float4*)p0)[j] = a;
            ((float4*)p1)[j] = c;
        }
    }
}

// ---------------- fallback: round-3 fused kernel (verified 248.8us) ----------
template<int NS>
__global__ __launch_bounds__(512, 4)
void butterfly_fused(const float* __restrict__ xsrc,
                     const float* __restrict__ vsrc,
                     float* __restrict__ vdst,
                     const unsigned short* __restrict__ PT,
                     int s0, int base_mul, int h_off, int rstride)
{
    extern __shared__ char smem[];
    unsigned short* xb   = (unsigned short*)smem;
    unsigned short* gbuf = (unsigned short*)(smem + GB_OFF);
    float*          wt   = (float*)(smem + WT_OFF_F);

    const int tid  = threadIdx.x;
    const int b    = blockIdx.x >> 6;
    const int sub  = blockIdx.x & 63;
    const int base = b * 8192 + sub * base_mul;
    {
        const int rl = tid >> 5, c4 = tid & 31;
#pragma unroll
        for (int j = 0; j < 8; ++j) {
            int i  = j * 16 + rl;
            int gp = base + (i >> 6) * h_off + (i & 63) * rstride;
            float4 val = ((const float4*)xsrc)[gp * 32 + c4];
            ushort4 us; us.x = f2bf(val.x); us.y = f2bf(val.y);
            us.z = f2bf(val.z); us.w = f2bf(val.w);
            *(ushort4*)(xb + i * XSTR + c4 * 4) = us;
        }
    }
    const int lane = tid & 63, w = tid >> 6;
    const int lane15 = lane & 15, quad = lane >> 4;
    const int rg = w >> 2, cg = w & 3;
    float vlo[16], vhi[16];
    {
        int r0 = 2 * lane, r1 = r0 + 1;
        int gp0 = base + (r0 >> 6) * h_off + (r0 & 63) * rstride;
        int gp1 = base + (r1 >> 6) * h_off + (r1 & 63) * rstride;
        const float* p0 = vsrc + (size_t)gp0 * 128 + w * 16;
        const float* p1 = vsrc + (size_t)gp1 * 128 + w * 16;
#pragma unroll
        for (int j = 0; j < 4; ++j) {
            float4 a = ((const float4*)p0)[j];
            float4 c = ((const float4*)p1)[j];
            vlo[4*j] = a.x; vlo[4*j+1] = a.y; vlo[4*j+2] = a.z; vlo[4*j+3] = a.w;
            vhi[4*j] = c.x; vhi[4*j+1] = c.y; vhi[4*j+2] = c.z; vhi[4*j+3] = c.w;
        }
    }
    __syncthreads();
#pragma unroll
    for (int u = 0; u < NS; ++u) {
        const int t   = 1 << u;
        const int tm1 = t - 1;
        {
            const uint4* Pf = (const uint4*)PT + (size_t)(s0 + u) * 2048;
            uint4 bfr[8];
#pragma unroll
            for (int ct = 0; ct < 2; ++ct)
#pragma unroll
                for (int kk = 0; kk < 4; ++kk)
                    bfr[ct * 4 + kk] = Pf[((cg * 2 + ct) * 4 + kk) * 64 + lane];
            const int m0 = rg * 32 + lane15, m1 = m0 + 16;
            const int ar0 = ((m0 & ~tm1) << 1) | (m0 & tm1);
            const int ar1 = ((m1 & ~tm1) << 1) | (m1 & tm1);
            f32x4 acc[2][2] = {};
#pragma unroll
            for (int kk = 0; kk < 4; ++kk) {
                bf16x8 a0 = *(const bf16x8*)(xb + ar0 * XSTR + kk * 32 + quad * 8);
                bf16x8 a1 = *(const bf16x8*)(xb + ar1 * XSTR + kk * 32 + quad * 8);
#pragma unroll
                for (int ct = 0; ct < 2; ++ct) {
                    union { uint4 u; bf16x8 b; } cv; cv.u = bfr[ct * 4 + kk];
                    acc[0][ct] = __builtin_amdgcn_mfma_f32_16x16x32_bf16(a0, cv.b, acc[0][ct], 0, 0, 0);
                    acc[1][ct] = __builtin_amdgcn_mfma_f32_16x16x32_bf16(a1, cv.b, acc[1][ct], 0, 0, 0);
                }
            }
#pragma unroll
            for (int rt = 0; rt < 2; ++rt)
#pragma unroll
                for (int ct = 0; ct < 2; ++ct)
#pragma unroll
                    for (int r = 0; r < 4; ++r)
                        gbuf[(rg * 32 + rt * 16 + quad * 4 + r) * GH_STR + cg * 32 + ct * 16 + lane15]
                            = f2bf(acc[rt][ct][r]);
        }
        __syncthreads();
        {
            const int half = lane >> 5, l32 = lane & 31, c0 = l32 * 4;
#pragma unroll
            for (int it = 0; it < 4; ++it) {
                int p  = w * 8 + it * 2 + half;
                int ar = ((p & ~tm1) << 1) | (p & tm1);
                int br = ar + t;
                uint2 ua = *(const uint2*)(xb + ar * XSTR + c0);
                uint2 ub = *(const uint2*)(xb + br * XSTR + c0);
                uint2 gg = *(const uint2*)(gbuf + p * GH_STR + c0);
                float a0 = ubits(ua.x << 16), a1 = ubits(ua.x & 0xffff0000u);
                float a2 = ubits(ua.y << 16), a3 = ubits(ua.y & 0xffff0000u);
                float b0 = ubits(ub.x << 16), b1 = ubits(ub.x & 0xffff0000u);
                float b2 = ubits(ub.y << 16), b3 = ubits(ub.y & 0xffff0000u);
                float g0 = ubits(gg.x << 16), g1 = ubits(gg.x & 0xffff0000u);
                float g2 = ubits(gg.y << 16), g3 = ubits(gg.y & 0xffff0000u);
                float sm = g0 * (a0 - b0) + g1 * (a1 - b1)
                         + g2 * (a2 - b2) + g3 * (a3 - b3);
                DPP_ADD_F(sm, 0x111);
                DPP_ADD_F(sm, 0x112);
                DPP_ADD_F(sm, 0x114);
                DPP_ADD_F(sm, 0x118);
                DPP_ADD_F(sm, 0x142);
                if (l32 == 31) wt[p] = 1.0f / (1.0f + __expf(-sm));
            }
        }
        __syncthreads();
        {
            const float w0 = wt[lane];
            if (u < NS - 1) {
                const bool isE = ((lane >> u) & 1) == 0;
                const float wk = isE ? w0 : 1.0f - w0;
#pragma unroll
                for (int j = 0; j < 16; ++j) {
                    float a = vlo[j], c = vhi[j];
                    float s    = a + c;
                    float keep = c + wk * (a - c);
                    float send = s - keep;
                    float ex   = xlane_u(send, u, lane);
                    vlo[j] = isE ? keep : ex;
                    vhi[j] = isE ? ex : keep;
                }
            } else {
                const float w1 = 1.0f - w0;
#pragma unroll
                for (int j = 0; j < 16; ++j) {
                    float a = vlo[j], c = vhi[j];
                    float oa = w0 * a + w1 * c;
                    vlo[j] = oa;
                    vhi[j] = a + c - oa;
                }
            }
        }
    }
    {
        const int FU = NS - 1;
        int r0 = ((lane >> FU) << (FU + 1)) | (lane & ((1 << FU) - 1));
        int r1 = r0 + (1 << FU);
        int gp0 = base + (r0 >> 6) * h_off + (r0 & 63) * rstride;
        int gp1 = base + (r1 >> 6) * h_off + (r1 & 63) * rstride;
        float* p0 = vdst + (size_t)gp0 * 128 + w * 16;
        float* p1 = vdst + (size_t)gp1 * 128 + w * 16;
#pragma unroll
        for (int j = 0; j < 4; ++j) {
            float4 a; a.x = vlo[4*j]; a.y = vlo[4*j+1]; a.z = vlo[4*j+2]; a.w = vlo[4*j+3];
            float4 c; c.x = vhi[4*j]; c.y = vhi[4*j+1]; c.z = vhi[4*j+2]; c.w = vhi[4*j+3];
            ((float4*)p0)[j] = a;
            ((float4*)p1)[j] = c;
        }
    }
}

extern "C" void kernel_launch(void* const* d_in, const int* in_sizes, int n_in,
                              void* d_out, int out_size, void* d_ws, size_t ws_size,
                              hipStream_t stream) {
    const float* x   = (const float*)d_in[0];
    const float* qkw = (const float*)d_in[1];
    float* out = (float*)d_out;
    unsigned short* PT = (unsigned short*)d_ws;   // 13*16384 bf16 = 416 KB

    (void)hipFuncSetAttribute((const void*)prep_kernel,
                              hipFuncAttributeMaxDynamicSharedMemorySize, PREP_LDS);

    prep_kernel<<<13, 512, PREP_LDS, stream>>>(qkw, PT);

    if (ws_size >= (size_t)WS_NEED) {
        float* dwt = (float*)((char*)d_ws + WS_DWT_OFF);
        (void)hipFuncSetAttribute((const void*)weights_kernel<7>,
                                  hipFuncAttributeMaxDynamicSharedMemorySize, LDS_W);
        (void)hipFuncSetAttribute((const void*)weights_kernel<6>,
                                  hipFuncAttributeMaxDynamicSharedMemorySize, LDS_W);

        // stages 0..6: contiguous 128-position blocks
        weights_kernel<7><<<1024, 512, LDS_W, stream>>>(
            x, PT, dwt, /*s0=*/0, /*base_mul=*/128, /*h_off=*/64, /*rstride=*/1);
        mix_kernel<7><<<1024, 512, 0, stream>>>(
            x, out, dwt, /*s0=*/0, /*base_mul=*/128, /*h_off=*/64, /*rstride=*/1);

        // stages 7..12: 2 lo x 64 hi (stride 128); in-place on d_out
        weights_kernel<6><<<1024, 512, LDS_W, stream>>>(
            x, PT, dwt, /*s0=*/7, /*base_mul=*/2, /*h_off=*/1, /*rstride=*/128);
        mix_kernel<6><<<1024, 512, 0, stream>>>(
            out, out, dwt, /*s0=*/7, /*base_mul=*/2, /*h_off=*/1, /*rstride=*/128);
    } else {
        // fallback: verified round-3 fused path
        (void)hipFuncSetAttribute((const void*)butterfly_fused<7>,
                                  hipFuncAttributeMaxDynamicSharedMemorySize, LDS_FUSED);
        (void)hipFuncSetAttribute((const void*)butterfly_fused<6>,
                                  hipFuncAttributeMaxDynamicSharedMemorySize, LDS_FUSED);
        butterfly_fused<7><<<1024, 512, LDS_FUSED, stream>>>(
            x, x, out, PT, 0, 128, 64, 1);
        butterfly_fused<6><<<1024, 512, LDS_FUSED, stream>>>(
            x, out, out, PT, 7, 2, 1, 128);
    }
}

// Round 7
// 223.256 us; speedup vs baseline: 1.4647x; 1.0913x over previous
//
#include <hip/hip_runtime.h>
#include <hip/hip_bf16.h>

// ---------------------------------------------------------------------------
// FFT butterfly attention. delta = x_a^T P (x_a - x_b), P = scale*Wq*Wk^T
// (bf16, MFMA prep). w0 = sigmoid(delta); v' = mix(va, vb).
//
// Split design (round-5, verified): weights depend only on x/PT, never v.
//  * weights8_kernel: wave w owns DIM-SLICE w*16..w*16+15 for ALL 64
//    pairs (was: 16 pairs x 64 dims). PT read per wave-stage drops 16KB->4KB
//    (4x less L2 traffic, the measured bottleneck: 918 MB/launch @34.5TB/s
//    ~= 27us of r5's 51us). Same 16 MFMA/stage, zero stage barriers.
//    Each pair's delta now has 8 partials (one per wave) -> dwt[...][8][64].
//  * mix_kernel: stages the 128x128 f32 v-tile through LDS so global
//    loads AND stores are coalesced float4 rows (r5 counters: WRITE_SIZE
//    123MB for 64MB output = x1.92 partial-sector inflation from 16B-per-
//    lane @512B-stride stores). Scatter now lives in LDS (cheap). Sums
//    NPART dwt partials per stage. 3 barriers total.
//  * tier-2 fallback if ws_size < 28.3MB: round-5's proven weights2 (2
//    partials, dwt 6.8MB) + new mix<NPART=2>.
//
// v register layout (pair-local): at stage u, lane L holds BOTH partners:
//   vlo = row ((L>>u)<<(u+1)) | (L & (2^u-1)),  vhi = vlo + 2^u
// (pair index of lane L == L; exchange partner lane L^2^u.)
// ---------------------------------------------------------------------------

typedef __bf16 bf16x8 __attribute__((ext_vector_type(8)));
typedef float  f32x4  __attribute__((ext_vector_type(4)));

#define XSTR 136                    // bf16 elems per xb row (128 + 8 pad)
#define XB_BYTES  (128 * XSTR * 2)  // 34816
#define PREP_LDS  (2 * XB_BYTES)    // 69632
#define LDS_W     XB_BYTES          // weights kernels: xb only

#define VSTR 132                    // f32 elems per mix vbuf row (16B-aligned)
#define LDS_MIX (128 * VSTR * 4)    // 67584 -> 2 WGs/CU

// workspace layout
#define WS_DWT_OFF (512 * 1024)                      // PT in [0, 416K)
#define DWT8_BYTES (13 * 1024 * 8 * 64 * 4)          // 27.26 MB
#define DWT2_BYTES (13 * 1024 * 128 * 4)             // 6.8 MB
#define WS_NEED8   (WS_DWT_OFF + DWT8_BYTES)
#define WS_NEED2   (WS_DWT_OFF + DWT2_BYTES)

__device__ __forceinline__ float ubits(unsigned int u) {
    union { unsigned int u; float f; } v; v.u = u; return v.f;
}
__device__ __forceinline__ unsigned short f2bf(float f) {
    union { float f; unsigned int u; } v; v.f = f;
    unsigned int u = v.u;
    return (unsigned short)((u + 0x7fffu + ((u >> 16) & 1u)) >> 16);
}

#define DPP_MOV_F(x, ctrl) \
    __int_as_float(__builtin_amdgcn_update_dpp(0, __float_as_int(x), (ctrl), 0xF, 0xF, true))

// cross-lane xor exchange with lane ^ (1<<u); u is compile-time-folded
__device__ __forceinline__ float xlane_u(float x, int u, int lane) {
    if (u == 0) return DPP_MOV_F(x, 0xB1);   // quad_perm xor1
    if (u == 1) return DPP_MOV_F(x, 0x4E);   // quad_perm xor2
    if (u == 2) return __int_as_float(__builtin_amdgcn_ds_swizzle(__float_as_int(x), 0x101F)); // xor4
    if (u == 3) return __int_as_float(__builtin_amdgcn_ds_swizzle(__float_as_int(x), 0x201F)); // xor8
    if (u == 4) return __int_as_float(__builtin_amdgcn_ds_swizzle(__float_as_int(x), 0x401F)); // xor16
    return __int_as_float(__builtin_amdgcn_ds_bpermute((lane ^ 32) << 2, __float_as_int(x))); // xor32
}

// ---------------- prep: PTf = fragment-major P^T -----------------------------
// frag (ci,kk) of 16-row tile ci at uint4 Pf[(ci*4+kk)*64 + lane]: 1KB coalesced.
__global__ __launch_bounds__(512)
void prep_kernel(const float* __restrict__ qkw, unsigned short* __restrict__ PT) {
    extern __shared__ char smem[];
    unsigned short* wkb = (unsigned short*)smem;              // A: Wk rows (n)
    unsigned short* wqb = (unsigned short*)(smem + XB_BYTES); // B: Wq rows (k)
    const int s = blockIdx.x;
    const float* Wq = qkw + (size_t)s * 32768;
    const float* Wk = Wq + 16384;
    const int tid = threadIdx.x;
    const int rl = tid >> 5, c4 = tid & 31;
#pragma unroll
    for (int j = 0; j < 8; ++j) {
        int r = j * 16 + rl;
        float4 vq = ((const float4*)Wq)[r * 32 + c4];
        float4 vk = ((const float4*)Wk)[r * 32 + c4];
        ushort4 uq; uq.x = f2bf(vq.x); uq.y = f2bf(vq.y); uq.z = f2bf(vq.z); uq.w = f2bf(vq.w);
        ushort4 uk; uk.x = f2bf(vk.x); uk.y = f2bf(vk.y); uk.z = f2bf(vk.z); uk.w = f2bf(vk.w);
        *(ushort4*)(wqb + r * XSTR + c4 * 4) = uq;
        *(ushort4*)(wkb + r * XSTR + c4 * 4) = uk;
    }
    __syncthreads();
    const int lane = tid & 63, w = tid >> 6;
    const int lane15 = lane & 15, quad = lane >> 4;
    f32x4 acc[8] = {};
#pragma unroll
    for (int kk = 0; kk < 4; ++kk) {
        bf16x8 a = *(const bf16x8*)(wkb + (w * 16 + lane15) * XSTR + kk * 32 + quad * 8);
#pragma unroll
        for (int ct = 0; ct < 8; ++ct) {
            bf16x8 b = *(const bf16x8*)(wqb + (ct * 16 + lane15) * XSTR + kk * 32 + quad * 8);
            acc[ct] = __builtin_amdgcn_mfma_f32_16x16x32_bf16(a, b, acc[ct], 0, 0, 0);
        }
    }
    // acc[ct][r] = PT[n][k], n = w*16 + quad*4 + r, k = ct*16 + lane15
    unsigned short* dst = PT + s * 16384;
#pragma unroll
    for (int ct = 0; ct < 8; ++ct) {
        const int kkf = ct >> 1;
        const int qf  = (ct & 1) * 2 + (lane15 >> 3);
        const int e   = lane15 & 7;
#pragma unroll
        for (int r = 0; r < 4; ++r) {
            int fi = (w * 4 + kkf) * 64 + qf * 16 + quad * 4 + r;
            dst[fi * 8 + e] = f2bf(acc[ct][r] * 0.17677669529663687f);
        }
    }
}

// ---------------- shared: stage x -> xb (bf16), coalesced --------------------
__device__ __forceinline__ void stage_xb(unsigned short* xb, const float* xsrc,
                                         int tid, int base, int h_off, int rstride) {
    const int rl = tid >> 5, c4 = tid & 31;
#pragma unroll
    for (int j = 0; j < 8; ++j) {
        int i  = j * 16 + rl;
        int gp = base + (i >> 6) * h_off + (i & 63) * rstride;
        float4 val = ((const float4*)xsrc)[gp * 32 + c4];
        ushort4 us; us.x = f2bf(val.x); us.y = f2bf(val.y);
        us.z = f2bf(val.z); us.w = f2bf(val.w);
        *(ushort4*)(xb + i * XSTR + c4 * 4) = us;
    }
}

// ---------------- weights8: dim-slice split, 8 partials, no stage barriers ---
template<int NS>
__global__ __launch_bounds__(512, 4)
void weights8_kernel(const float* __restrict__ xsrc,
                     const unsigned short* __restrict__ PT,
                     float* __restrict__ dwt,
                     int s0, int base_mul, int h_off, int rstride)
{
    extern __shared__ char smem[];
    unsigned short* xb = (unsigned short*)smem;

    const int tid  = threadIdx.x;
    const int b    = blockIdx.x >> 6;
    const int sub  = blockIdx.x & 63;
    const int base = b * 8192 + sub * base_mul;

    stage_xb(xb, xsrc, tid, base, h_off, rstride);

    const int lane = tid & 63, w = tid >> 6;
    const int lane15 = lane & 15, quad = lane >> 4;

    __syncthreads();   // xb ready; NO further barriers (xb read-only below)

#pragma unroll
    for (int u = 0; u < NS; ++u) {
        const int t   = 1 << u;
        const int tm1 = t - 1;

        // A-frags: PTf frags (w, kk) -> 4 KB per wave-stage, coalesced.
        const uint4* Pf = (const uint4*)PT + (size_t)(s0 + u) * 2048;
        uint4 af[4];
#pragma unroll
        for (int kk = 0; kk < 4; ++kk)
            af[kk] = Pf[(w * 4 + kk) * 64 + lane];

        // Gt tile: dims w*16..+15 (C rows), pairs pg*16+lane15 (C cols).
        f32x4 acc[4] = {};
#pragma unroll
        for (int pg = 0; pg < 4; ++pg) {
            const int p  = pg * 16 + lane15;
            const int ar = ((p & ~tm1) << 1) | (p & tm1);
            const unsigned short* brow = xb + ar * XSTR + quad * 8;
#pragma unroll
            for (int kk = 0; kk < 4; ++kk) {
                bf16x8 bfrag = *(const bf16x8*)(brow + kk * 32);
                union { uint4 u; bf16x8 b; } av; av.u = af[kk];
                acc[pg] = __builtin_amdgcn_mfma_f32_16x16x32_bf16(av.b, bfrag, acc[pg], 0, 0, 0);
            }
        }

        // partial dot over this wave's 16 dims; reduce quads via xor16+xor32
        float sm[4];
#pragma unroll
        for (int pg = 0; pg < 4; ++pg) {
            const int p  = pg * 16 + lane15;
            const int ar = ((p & ~tm1) << 1) | (p & tm1);
            const unsigned short* da = xb + ar * XSTR + w * 16 + quad * 4;
            const unsigned short* db = da + t * XSTR;
            uint2 ua = *(const uint2*)da;
            uint2 ub = *(const uint2*)db;
            float a0 = ubits(ua.x << 16), a1 = ubits(ua.x & 0xffff0000u);
            float a2 = ubits(ua.y << 16), a3 = ubits(ua.y & 0xffff0000u);
            float b0 = ubits(ub.x << 16), b1 = ubits(ub.x & 0xffff0000u);
            float b2 = ubits(ub.y << 16), b3 = ubits(ub.y & 0xffff0000u);
            float s = acc[pg][0] * (a0 - b0) + acc[pg][1] * (a1 - b1)
                    + acc[pg][2] * (a2 - b2) + acc[pg][3] * (a3 - b3);
            s += xlane_u(s, 4, lane);
            s += xlane_u(s, 5, lane);
            sm[pg] = s;
        }
        // all lanes hold totals; lane L stores pair L's partial (coalesced 256B)
        float v = (lane & 32) ? ((lane & 16) ? sm[3] : sm[2])
                              : ((lane & 16) ? sm[1] : sm[0]);
        dwt[(((size_t)(s0 + u) * 1024 + blockIdx.x) * 8 + w) * 64 + lane] = v;
    }
}

// ---------------- weights2: round-5 verified (2 partials, dwt 6.8MB) ---------
template<int NS>
__global__ __launch_bounds__(512, 4)
void weights2_kernel(const float* __restrict__ xsrc,
                     const unsigned short* __restrict__ PT,
                     float* __restrict__ dwt,
                     int s0, int base_mul, int h_off, int rstride)
{
    extern __shared__ char smem[];
    unsigned short* xb = (unsigned short*)smem;

    const int tid  = threadIdx.x;
    const int b    = blockIdx.x >> 6;
    const int sub  = blockIdx.x & 63;
    const int base = b * 8192 + sub * base_mul;

    stage_xb(xb, xsrc, tid, base, h_off, rstride);

    const int lane = tid & 63, w = tid >> 6;
    const int lane15 = lane & 15, quad = lane >> 4;
    const int nt = w & 3;
    const int mh = w >> 2;
    const int p  = nt * 16 + lane15;

    __syncthreads();

#pragma unroll
    for (int u = 0; u < NS; ++u) {
        const int t   = 1 << u;
        const int tm1 = t - 1;
        const int ar  = ((p & ~tm1) << 1) | (p & tm1);

        float sm = 0.f;
        {
            const uint4* Pf = (const uint4*)PT + (size_t)(s0 + u) * 2048;
            const unsigned short* brow = xb + ar * XSTR + quad * 8;
            f32x4 acc[4] = {};
#pragma unroll
            for (int kk = 0; kk < 4; ++kk) {
                bf16x8 bfrag = *(const bf16x8*)(brow + kk * 32);
#pragma unroll
                for (int mt = 0; mt < 4; ++mt) {
                    union { uint4 u; bf16x8 b; } av;
                    av.u = Pf[((mh * 4 + mt) * 4 + kk) * 64 + lane];
                    acc[mt] = __builtin_amdgcn_mfma_f32_16x16x32_bf16(av.b, bfrag, acc[mt], 0, 0, 0);
                }
            }
            const unsigned short* da = xb + ar * XSTR + mh * 64 + quad * 4;
            const unsigned short* db = da + t * XSTR;
#pragma unroll
            for (int mt = 0; mt < 4; ++mt) {
                uint2 ua = *(const uint2*)(da + mt * 16);
                uint2 ub = *(const uint2*)(db + mt * 16);
                float a0 = ubits(ua.x << 16), a1 = ubits(ua.x & 0xffff0000u);
                float a2 = ubits(ua.y << 16), a3 = ubits(ua.y & 0xffff0000u);
                float b0 = ubits(ub.x << 16), b1 = ubits(ub.x & 0xffff0000u);
                float b2 = ubits(ub.y << 16), b3 = ubits(ub.y & 0xffff0000u);
                sm += acc[mt][0] * (a0 - b0) + acc[mt][1] * (a1 - b1)
                    + acc[mt][2] * (a2 - b2) + acc[mt][3] * (a3 - b3);
            }
        }
        sm += xlane_u(sm, 4, lane);
        sm += xlane_u(sm, 5, lane);
        if (lane < 16)
            dwt[((size_t)(s0 + u) * 1024 + blockIdx.x) * 128 + mh * 64 + nt * 16 + lane] = sm;
    }
}

// ---------------- mix: LDS-staged coalesced I/O, register butterfly ----------
template<int NS, int NPART>
__global__ __launch_bounds__(512, 4)
void mix_kernel(const float* __restrict__ vsrc,
                float* __restrict__ vdst,
                const float* __restrict__ dwt,
                int s0, int base_mul, int h_off, int rstride)
{
    extern __shared__ char smem[];
    float* vbuf = (float*)smem;   // [128][VSTR]

    const int tid  = threadIdx.x;
    const int b    = blockIdx.x >> 6;
    const int sub  = blockIdx.x & 63;
    const int base = b * 8192 + sub * base_mul;
    const int lane = tid & 63, w = tid >> 6;
    const int rl = tid >> 5, c4 = tid & 31;

    // ---- coalesced load v -> vbuf ----
#pragma unroll
    for (int j = 0; j < 8; ++j) {
        int i  = j * 16 + rl;
        int gp = base + (i >> 6) * h_off + (i & 63) * rstride;
        float4 val = ((const float4*)vsrc)[gp * 32 + c4];
        *(float4*)(vbuf + i * VSTR + c4 * 4) = val;
    }
    __syncthreads();

    // ---- distribute: lane L holds rows (2L, 2L+1), dims w*16..+15 ----
    float vlo[16], vhi[16];
    {
        const float* p0 = vbuf + (2 * lane) * VSTR + w * 16;
        const float* p1 = p0 + VSTR;
#pragma unroll
        for (int j = 0; j < 4; ++j) {
            float4 a = *(const float4*)(p0 + 4 * j);
            float4 c = *(const float4*)(p1 + 4 * j);
            vlo[4*j] = a.x; vlo[4*j+1] = a.y; vlo[4*j+2] = a.z; vlo[4*j+3] = a.w;
            vhi[4*j] = c.x; vhi[4*j+1] = c.y; vhi[4*j+2] = c.z; vhi[4*j+3] = c.w;
        }
    }

#pragma unroll
    for (int u = 0; u < NS; ++u) {
        const float* dw = dwt + ((size_t)(s0 + u) * 1024 + blockIdx.x) * (NPART * 64);
        float d = 0.f;
#pragma unroll
        for (int k = 0; k < NPART; ++k) d += dw[k * 64 + lane];
        const float w0 = 1.0f / (1.0f + __expf(-d));
        if (u < NS - 1) {
            const bool isE = ((lane >> u) & 1) == 0;
            const float wk = isE ? w0 : 1.0f - w0;
#pragma unroll
            for (int j = 0; j < 16; ++j) {
                float a = vlo[j], c = vhi[j];
                float s    = a + c;
                float keep = c + wk * (a - c);   // E: out_a ; O: out_b
                float send = s - keep;           // E: out_b ; O: out_a
                float ex   = xlane_u(send, u, lane);
                vlo[j] = isE ? keep : ex;
                vhi[j] = isE ? ex : keep;
            }
        } else {
            const float w1 = 1.0f - w0;
#pragma unroll
            for (int j = 0; j < 16; ++j) {
                float a = vlo[j], c = vhi[j];
                float oa = w0 * a + w1 * c;
                vlo[j] = oa;
                vhi[j] = a + c - oa;
            }
        }
    }

    __syncthreads();   // all vbuf reads done before overwrite

    // ---- write registers back to vbuf (final-stage layout) ----
    {
        const int FU = NS - 1;
        int r0 = ((lane >> FU) << (FU + 1)) | (lane & ((1 << FU) - 1));
        int r1 = r0 + (1 << FU);
        float* q0 = vbuf + r0 * VSTR + w * 16;
        float* q1 = vbuf + r1 * VSTR + w * 16;
#pragma unroll
        for (int j = 0; j < 4; ++j) {
            float4 a; a.x = vlo[4*j]; a.y = vlo[4*j+1]; a.z = vlo[4*j+2]; a.w = vlo[4*j+3];
            float4 c; c.x = vhi[4*j]; c.y = vhi[4*j+1]; c.z = vhi[4*j+2]; c.w = vhi[4*j+3];
            *(float4*)(q0 + 4 * j) = a;
            *(float4*)(q1 + 4 * j) = c;
        }
    }
    __syncthreads();

    // ---- coalesced store vbuf -> vdst ----
#pragma unroll
    for (int j = 0; j < 8; ++j) {
        int i  = j * 16 + rl;
        int gp = base + (i >> 6) * h_off + (i & 63) * rstride;
        ((float4*)vdst)[gp * 32 + c4] = *(const float4*)(vbuf + i * VSTR + c4 * 4);
    }
}

extern "C" void kernel_launch(void* const* d_in, const int* in_sizes, int n_in,
                              void* d_out, int out_size, void* d_ws, size_t ws_size,
                              hipStream_t stream) {
    const float* x   = (const float*)d_in[0];
    const float* qkw = (const float*)d_in[1];
    float* out = (float*)d_out;
    unsigned short* PT = (unsigned short*)d_ws;   // 13*16384 bf16 = 416 KB
    float* dwt = (float*)((char*)d_ws + WS_DWT_OFF);

    (void)hipFuncSetAttribute((const void*)prep_kernel,
                              hipFuncAttributeMaxDynamicSharedMemorySize, PREP_LDS);

    prep_kernel<<<13, 512, PREP_LDS, stream>>>(qkw, PT);

    if (ws_size >= (size_t)WS_NEED8) {
        (void)hipFuncSetAttribute((const void*)weights8_kernel<7>,
                                  hipFuncAttributeMaxDynamicSharedMemorySize, LDS_W);
        (void)hipFuncSetAttribute((const void*)weights8_kernel<6>,
                                  hipFuncAttributeMaxDynamicSharedMemorySize, LDS_W);
        (void)hipFuncSetAttribute((const void*)mix_kernel<7,8>,
                                  hipFuncAttributeMaxDynamicSharedMemorySize, LDS_MIX);
        (void)hipFuncSetAttribute((const void*)mix_kernel<6,8>,
                                  hipFuncAttributeMaxDynamicSharedMemorySize, LDS_MIX);

        weights8_kernel<7><<<1024, 512, LDS_W, stream>>>(
            x, PT, dwt, /*s0=*/0, /*base_mul=*/128, /*h_off=*/64, /*rstride=*/1);
        mix_kernel<7,8><<<1024, 512, LDS_MIX, stream>>>(
            x, out, dwt, /*s0=*/0, /*base_mul=*/128, /*h_off=*/64, /*rstride=*/1);
        weights8_kernel<6><<<1024, 512, LDS_W, stream>>>(
            x, PT, dwt, /*s0=*/7, /*base_mul=*/2, /*h_off=*/1, /*rstride=*/128);
        mix_kernel<6,8><<<1024, 512, LDS_MIX, stream>>>(
            out, out, dwt, /*s0=*/7, /*base_mul=*/2, /*h_off=*/1, /*rstride=*/128);
    } else {
        // tier-2: round-5 verified weights (dwt 6.8MB) + improved mix
        (void)hipFuncSetAttribute((const void*)weights2_kernel<7>,
                                  hipFuncAttributeMaxDynamicSharedMemorySize, LDS_W);
        (void)hipFuncSetAttribute((const void*)weights2_kernel<6>,
                                  hipFuncAttributeMaxDynamicSharedMemorySize, LDS_W);
        (void)hipFuncSetAttribute((const void*)mix_kernel<7,2>,
                                  hipFuncAttributeMaxDynamicSharedMemorySize, LDS_MIX);
        (void)hipFuncSetAttribute((const void*)mix_kernel<6,2>,
                                  hipFuncAttributeMaxDynamicSharedMemorySize, LDS_MIX);

        weights2_kernel<7><<<1024, 512, LDS_W, stream>>>(
            x, PT, dwt, 0, 128, 64, 1);
        mix_kernel<7,2><<<1024, 512, LDS_MIX, stream>>>(
            x, out, dwt, 0, 128, 64, 1);
        weights2_kernel<6><<<1024, 512, LDS_W, stream>>>(
            x, PT, dwt, 7, 2, 1, 128);
        mix_kernel<6,2><<<1024, 512, LDS_MIX, stream>>>(
            out, out, dwt, 7, 2, 1, 128);
    }
}

// Round 8
// 205.957 us; speedup vs baseline: 1.5878x; 1.0840x over previous
//
#include <hip/hip_runtime.h>
#include <hip/hip_bf16.h>

// ---------------------------------------------------------------------------
// FFT butterfly attention. delta = x_a^T P (x_a - x_b), P = scale*Wq*Wk^T
// (bf16, MFMA prep). w0 = sigmoid(delta); v' = mix(va, vb).
//
// Split design (r5/r7 verified): weights depend only on x/PT, never v.
//  * weights4_kernel (NEW): balanced 2x2 wave tiling (dh = w>>1 owns dims
//    dh*32..+31; ph = w&1 owns pairs ph*32..+31). B-frag LDS reads 16->8 per
//    wave-stage (r7's measured LDS-throughput bottleneck), PT 4->8KB (L2,
//    overlappable). xb is XOR-SWIZZLED (XW=128, swz(r)=((r>>1)^(r>>2))&15,
//    16B slots): <=2-way banks on B-frag & dot reads at ALL stages (stage-0
//    even-row 8-way conflict killed; r7: 6.1M conflicts). 4 partials/pair.
//  * mix_kernel (NEW): distribute v from GLOBAL (r5-verified read path;
//    L3 absorbs the 16B@512B scatter), register butterfly, then LDS-stage
//    ONLY the output for coalesced float4 stores (r5: write inflation x1.92
//    was the measured cost). vbuf XOR-swizzled (slot ^ row&31): writeback
//    and store both conflict-free. ONE barrier total.
//  * tier-2 fallback (ws < 14.2MB): r5-verified weights2 + mix<NPART=2>.
//
// v register layout (pair-local): at stage u, lane L holds BOTH partners:
//   vlo = row ((L>>u)<<(u+1)) | (L & (2^u-1)),  vhi = vlo + 2^u
// (pair index of lane L == L; exchange partner lane L^2^u.)
// ---------------------------------------------------------------------------

typedef __bf16 bf16x8 __attribute__((ext_vector_type(8)));
typedef float  f32x4  __attribute__((ext_vector_type(4)));

#define XSTR 136                    // bf16/row, UNswizzled xb (prep + weights2)
#define XB_BYTES  (128 * XSTR * 2)  // 34816
#define PREP_LDS  (2 * XB_BYTES)    // 69632
#define LDS_W2    XB_BYTES          // weights2: unswizzled xb

#define XW 128                      // bf16/row, swizzled xb (weights4)
#define LDS_W4    (128 * XW * 2)    // 32768

#define LDS_MIX   (128 * 128 * 4)   // 65536 (vbuf, swizzled)

// workspace layout
#define WS_DWT_OFF (512 * 1024)                      // PT in [0, 416K)
#define DWT4_BYTES (13 * 1024 * 4 * 64 * 4)          // 13.6 MB
#define WS_NEED4   (WS_DWT_OFF + DWT4_BYTES)

__device__ __forceinline__ float ubits(unsigned int u) {
    union { unsigned int u; float f; } v; v.u = u; return v.f;
}
__device__ __forceinline__ unsigned short f2bf(float f) {
    union { float f; unsigned int u; } v; v.f = f;
    unsigned int u = v.u;
    return (unsigned short)((u + 0x7fffu + ((u >> 16) & 1u)) >> 16);
}
__device__ __forceinline__ int swzr(int r) { return ((r >> 1) ^ (r >> 2)) & 15; }

#define DPP_MOV_F(x, ctrl) \
    __int_as_float(__builtin_amdgcn_update_dpp(0, __float_as_int(x), (ctrl), 0xF, 0xF, true))

// cross-lane xor exchange with lane ^ (1<<u); u is compile-time-folded
__device__ __forceinline__ float xlane_u(float x, int u, int lane) {
    if (u == 0) return DPP_MOV_F(x, 0xB1);   // quad_perm xor1
    if (u == 1) return DPP_MOV_F(x, 0x4E);   // quad_perm xor2
    if (u == 2) return __int_as_float(__builtin_amdgcn_ds_swizzle(__float_as_int(x), 0x101F)); // xor4
    if (u == 3) return __int_as_float(__builtin_amdgcn_ds_swizzle(__float_as_int(x), 0x201F)); // xor8
    if (u == 4) return __int_as_float(__builtin_amdgcn_ds_swizzle(__float_as_int(x), 0x401F)); // xor16
    return __int_as_float(__builtin_amdgcn_ds_bpermute((lane ^ 32) << 2, __float_as_int(x))); // xor32
}

// ---------------- prep: PTf = fragment-major P^T -----------------------------
// frag (ci,kk) of 16-row tile ci at uint4 Pf[(ci*4+kk)*64 + lane]: 1KB coalesced.
__global__ __launch_bounds__(512)
void prep_kernel(const float* __restrict__ qkw, unsigned short* __restrict__ PT) {
    extern __shared__ char smem[];
    unsigned short* wkb = (unsigned short*)smem;              // A: Wk rows (n)
    unsigned short* wqb = (unsigned short*)(smem + XB_BYTES); // B: Wq rows (k)
    const int s = blockIdx.x;
    const float* Wq = qkw + (size_t)s * 32768;
    const float* Wk = Wq + 16384;
    const int tid = threadIdx.x;
    const int rl = tid >> 5, c4 = tid & 31;
#pragma unroll
    for (int j = 0; j < 8; ++j) {
        int r = j * 16 + rl;
        float4 vq = ((const float4*)Wq)[r * 32 + c4];
        float4 vk = ((const float4*)Wk)[r * 32 + c4];
        ushort4 uq; uq.x = f2bf(vq.x); uq.y = f2bf(vq.y); uq.z = f2bf(vq.z); uq.w = f2bf(vq.w);
        ushort4 uk; uk.x = f2bf(vk.x); uk.y = f2bf(vk.y); uk.z = f2bf(vk.z); uk.w = f2bf(vk.w);
        *(ushort4*)(wqb + r * XSTR + c4 * 4) = uq;
        *(ushort4*)(wkb + r * XSTR + c4 * 4) = uk;
    }
    __syncthreads();
    const int lane = tid & 63, w = tid >> 6;
    const int lane15 = lane & 15, quad = lane >> 4;
    f32x4 acc[8] = {};
#pragma unroll
    for (int kk = 0; kk < 4; ++kk) {
        bf16x8 a = *(const bf16x8*)(wkb + (w * 16 + lane15) * XSTR + kk * 32 + quad * 8);
#pragma unroll
        for (int ct = 0; ct < 8; ++ct) {
            bf16x8 b = *(const bf16x8*)(wqb + (ct * 16 + lane15) * XSTR + kk * 32 + quad * 8);
            acc[ct] = __builtin_amdgcn_mfma_f32_16x16x32_bf16(a, b, acc[ct], 0, 0, 0);
        }
    }
    // acc[ct][r] = PT[n][k], n = w*16 + quad*4 + r, k = ct*16 + lane15
    unsigned short* dst = PT + s * 16384;
#pragma unroll
    for (int ct = 0; ct < 8; ++ct) {
        const int kkf = ct >> 1;
        const int qf  = (ct & 1) * 2 + (lane15 >> 3);
        const int e   = lane15 & 7;
#pragma unroll
        for (int r = 0; r < 4; ++r) {
            int fi = (w * 4 + kkf) * 64 + qf * 16 + quad * 4 + r;
            dst[fi * 8 + e] = f2bf(acc[ct][r] * 0.17677669529663687f);
        }
    }
}

// ---------------- staging helpers -------------------------------------------
__device__ __forceinline__ void stage_xb(unsigned short* xb, const float* xsrc,
                                         int tid, int base, int h_off, int rstride) {
    const int rl = tid >> 5, c4 = tid & 31;
#pragma unroll
    for (int j = 0; j < 8; ++j) {
        int i  = j * 16 + rl;
        int gp = base + (i >> 6) * h_off + (i & 63) * rstride;
        float4 val = ((const float4*)xsrc)[gp * 32 + c4];
        ushort4 us; us.x = f2bf(val.x); us.y = f2bf(val.y);
        us.z = f2bf(val.z); us.w = f2bf(val.w);
        *(ushort4*)(xb + i * XSTR + c4 * 4) = us;
    }
}

// swizzled: row i, 16B slot s lives at byte i*256 + ((s ^ swzr(i))*16)
__device__ __forceinline__ void stage_xb_swz(unsigned short* xb, const float* xsrc,
                                             int tid, int base, int h_off, int rstride) {
    const int rl = tid >> 5, c4 = tid & 31;
#pragma unroll
    for (int j = 0; j < 8; ++j) {
        int i  = j * 16 + rl;
        int gp = base + (i >> 6) * h_off + (i & 63) * rstride;
        float4 val = ((const float4*)xsrc)[gp * 32 + c4];
        ushort4 us; us.x = f2bf(val.x); us.y = f2bf(val.y);
        us.z = f2bf(val.z); us.w = f2bf(val.w);
        int slot = c4 >> 1, half = c4 & 1;
        *(ushort4*)(xb + i * XW + (((slot ^ swzr(i)) << 3) + half * 4)) = us;
    }
}

// ---------------- weights4: 2x2 tiling, swizzled xb, 4 partials --------------
template<int NS>
__global__ __launch_bounds__(512, 4)
void weights4_kernel(const float* __restrict__ xsrc,
                     const unsigned short* __restrict__ PT,
                     float* __restrict__ dwt,
                     int s0, int base_mul, int h_off, int rstride)
{
    extern __shared__ char smem[];
    unsigned short* xb = (unsigned short*)smem;   // swizzled [128][XW]

    const int tid  = threadIdx.x;
    const int b    = blockIdx.x >> 6;
    const int sub  = blockIdx.x & 63;
    const int base = b * 8192 + sub * base_mul;

    stage_xb_swz(xb, xsrc, tid, base, h_off, rstride);

    const int lane = tid & 63, w = tid >> 6;
    const int lane15 = lane & 15, quad = lane >> 4;
    const int dh = w >> 1;            // dim-slice: dims dh*32..+31
    const int ph = w & 1;             // pair-slice: pairs ph*32..+31

    __syncthreads();   // xb ready; NO further barriers (xb read-only below)

#pragma unroll
    for (int u = 0; u < NS; ++u) {
        const int t   = 1 << u;
        const int tm1 = t - 1;

        // A-frags: PTf frags (dh*2+mt, kk) -> 8KB/wave-stage, coalesced.
        const uint4* Pf = (const uint4*)PT + (size_t)(s0 + u) * 2048;
        uint4 af[2][4];
#pragma unroll
        for (int mt = 0; mt < 2; ++mt)
#pragma unroll
            for (int kk = 0; kk < 4; ++kk)
                af[mt][kk] = Pf[((dh * 2 + mt) * 4 + kk) * 64 + lane];

        // Gt subtile: dims dh*32..+31 (C rows), pairs ph*32..+31 (C cols)
        f32x4 acc[2][2] = {};
#pragma unroll
        for (int pg = 0; pg < 2; ++pg) {
            const int p  = (ph * 2 + pg) * 16 + lane15;
            const int ar = ((p & ~tm1) << 1) | (p & tm1);
            const int swa = swzr(ar);
            const unsigned short* brow = xb + ar * XW;
#pragma unroll
            for (int kk = 0; kk < 4; ++kk) {
                bf16x8 bfrag = *(const bf16x8*)(brow + (((kk * 4 + quad) ^ swa) << 3));
#pragma unroll
                for (int mt = 0; mt < 2; ++mt) {
                    union { uint4 u; bf16x8 b; } av; av.u = af[mt][kk];
                    acc[mt][pg] = __builtin_amdgcn_mfma_f32_16x16x32_bf16(av.b, bfrag, acc[mt][pg], 0, 0, 0);
                }
            }
        }

        // partial dot over dims dh*32..+31; quad-reduce via xor16+xor32
        float sm[2];
#pragma unroll
        for (int pg = 0; pg < 2; ++pg) {
            const int p  = (ph * 2 + pg) * 16 + lane15;
            const int ar = ((p & ~tm1) << 1) | (p & tm1);
            const int br = ar + t;
            const int swa = swzr(ar), swb = swzr(br);
            float s = 0.f;
#pragma unroll
            for (int mt = 0; mt < 2; ++mt) {
                const int slot = dh * 4 + mt * 2 + (quad >> 1);
                uint2 ua = *(const uint2*)(xb + ar * XW + (((slot ^ swa) << 3) + (quad & 1) * 4));
                uint2 ub = *(const uint2*)(xb + br * XW + (((slot ^ swb) << 3) + (quad & 1) * 4));
                float a0 = ubits(ua.x << 16), a1 = ubits(ua.x & 0xffff0000u);
                float a2 = ubits(ua.y << 16), a3 = ubits(ua.y & 0xffff0000u);
                float b0 = ubits(ub.x << 16), b1 = ubits(ub.x & 0xffff0000u);
                float b2 = ubits(ub.y << 16), b3 = ubits(ub.y & 0xffff0000u);
                s += acc[mt][pg][0] * (a0 - b0) + acc[mt][pg][1] * (a1 - b1)
                   + acc[mt][pg][2] * (a2 - b2) + acc[mt][pg][3] * (a3 - b3);
            }
            s += xlane_u(s, 4, lane);
            s += xlane_u(s, 5, lane);
            sm[pg] = s;
        }
        // lanes 0..31 store pairs ph*32 + (lane&31), partial dh (coalesced 128B)
        float v = (lane & 16) ? sm[1] : sm[0];
        if (lane < 32)
            dwt[(((size_t)(s0 + u) * 1024 + blockIdx.x) * 4 + dh) * 64 + ph * 32 + (lane & 31)] = v;
    }
}

// ---------------- weights2: r5-verified fallback (2 partials) ----------------
template<int NS>
__global__ __launch_bounds__(512, 4)
void weights2_kernel(const float* __restrict__ xsrc,
                     const unsigned short* __restrict__ PT,
                     float* __restrict__ dwt,
                     int s0, int base_mul, int h_off, int rstride)
{
    extern __shared__ char smem[];
    unsigned short* xb = (unsigned short*)smem;

    const int tid  = threadIdx.x;
    const int b    = blockIdx.x >> 6;
    const int sub  = blockIdx.x & 63;
    const int base = b * 8192 + sub * base_mul;

    stage_xb(xb, xsrc, tid, base, h_off, rstride);

    const int lane = tid & 63, w = tid >> 6;
    const int lane15 = lane & 15, quad = lane >> 4;
    const int nt = w & 3;
    const int mh = w >> 2;
    const int p  = nt * 16 + lane15;

    __syncthreads();

#pragma unroll
    for (int u = 0; u < NS; ++u) {
        const int t   = 1 << u;
        const int tm1 = t - 1;
        const int ar  = ((p & ~tm1) << 1) | (p & tm1);

        float sm = 0.f;
        {
            const uint4* Pf = (const uint4*)PT + (size_t)(s0 + u) * 2048;
            const unsigned short* brow = xb + ar * XSTR + quad * 8;
            f32x4 acc[4] = {};
#pragma unroll
            for (int kk = 0; kk < 4; ++kk) {
                bf16x8 bfrag = *(const bf16x8*)(brow + kk * 32);
#pragma unroll
                for (int mt = 0; mt < 4; ++mt) {
                    union { uint4 u; bf16x8 b; } av;
                    av.u = Pf[((mh * 4 + mt) * 4 + kk) * 64 + lane];
                    acc[mt] = __builtin_amdgcn_mfma_f32_16x16x32_bf16(av.b, bfrag, acc[mt], 0, 0, 0);
                }
            }
            const unsigned short* da = xb + ar * XSTR + mh * 64 + quad * 4;
            const unsigned short* db = da + t * XSTR;
#pragma unroll
            for (int mt = 0; mt < 4; ++mt) {
                uint2 ua = *(const uint2*)(da + mt * 16);
                uint2 ub = *(const uint2*)(db + mt * 16);
                float a0 = ubits(ua.x << 16), a1 = ubits(ua.x & 0xffff0000u);
                float a2 = ubits(ua.y << 16), a3 = ubits(ua.y & 0xffff0000u);
                float b0 = ubits(ub.x << 16), b1 = ubits(ub.x & 0xffff0000u);
                float b2 = ubits(ub.y << 16), b3 = ubits(ub.y & 0xffff0000u);
                sm += acc[mt][0] * (a0 - b0) + acc[mt][1] * (a1 - b1)
                    + acc[mt][2] * (a2 - b2) + acc[mt][3] * (a3 - b3);
            }
        }
        sm += xlane_u(sm, 4, lane);
        sm += xlane_u(sm, 5, lane);
        if (lane < 16)
            dwt[((size_t)(s0 + u) * 1024 + blockIdx.x) * 128 + mh * 64 + nt * 16 + lane] = sm;
    }
}

// ---------------- mix: global distribute, LDS-staged coalesced store ---------
template<int NS, int NPART>
__global__ __launch_bounds__(512, 4)
void mix_kernel(const float* __restrict__ vsrc,
                float* __restrict__ vdst,
                const float* __restrict__ dwt,
                int s0, int base_mul, int h_off, int rstride)
{
    extern __shared__ char smem[];
    float* vbuf = (float*)smem;   // [128][128], 16B slots XOR'd by (row&31)

    const int tid  = threadIdx.x;
    const int b    = blockIdx.x >> 6;
    const int sub  = blockIdx.x & 63;
    const int base = b * 8192 + sub * base_mul;
    const int lane = tid & 63, w = tid >> 6;
    const int rl = tid >> 5, c4 = tid & 31;

    // ---- distribute directly from global (r5-verified path; L3 absorbs) ----
    float vlo[16], vhi[16];
    {
        int r0 = 2 * lane, r1 = r0 + 1;
        int gp0 = base + (r0 >> 6) * h_off + (r0 & 63) * rstride;
        int gp1 = base + (r1 >> 6) * h_off + (r1 & 63) * rstride;
        const float* p0 = vsrc + (size_t)gp0 * 128 + w * 16;
        const float* p1 = vsrc + (size_t)gp1 * 128 + w * 16;
#pragma unroll
        for (int j = 0; j < 4; ++j) {
            float4 a = ((const float4*)p0)[j];
            float4 c = ((const float4*)p1)[j];
            vlo[4*j] = a.x; vlo[4*j+1] = a.y; vlo[4*j+2] = a.z; vlo[4*j+3] = a.w;
            vhi[4*j] = c.x; vhi[4*j+1] = c.y; vhi[4*j+2] = c.z; vhi[4*j+3] = c.w;
        }
    }

#pragma unroll
    for (int u = 0; u < NS; ++u) {
        const float* dw = dwt + ((size_t)(s0 + u) * 1024 + blockIdx.x) * (NPART * 64);
        float d = 0.f;
#pragma unroll
        for (int k = 0; k < NPART; ++k) d += dw[k * 64 + lane];
        const float w0 = 1.0f / (1.0f + __expf(-d));
        if (u < NS - 1) {
            const bool isE = ((lane >> u) & 1) == 0;
            const float wk = isE ? w0 : 1.0f - w0;
#pragma unroll
            for (int j = 0; j < 16; ++j) {
                float a = vlo[j], c = vhi[j];
                float s    = a + c;
                float keep = c + wk * (a - c);   // E: out_a ; O: out_b
                float send = s - keep;           // E: out_b ; O: out_a
                float ex   = xlane_u(send, u, lane);
                vlo[j] = isE ? keep : ex;
                vhi[j] = isE ? ex : keep;
            }
        } else {
            const float w1 = 1.0f - w0;
#pragma unroll
            for (int j = 0; j < 16; ++j) {
                float a = vlo[j], c = vhi[j];
                float oa = w0 * a + w1 * c;
                vlo[j] = oa;
                vhi[j] = a + c - oa;
            }
        }
    }

    // ---- write registers to swizzled vbuf (final-stage layout) ----
    {
        const int FU = NS - 1;
        int r0 = ((lane >> FU) << (FU + 1)) | (lane & ((1 << FU) - 1));
        int r1 = r0 + (1 << FU);
#pragma unroll
        for (int j = 0; j < 4; ++j) {
            float4 a; a.x = vlo[4*j]; a.y = vlo[4*j+1]; a.z = vlo[4*j+2]; a.w = vlo[4*j+3];
            float4 c; c.x = vhi[4*j]; c.y = vhi[4*j+1]; c.z = vhi[4*j+2]; c.w = vhi[4*j+3];
            int slot = w * 4 + j;
            *(float4*)(vbuf + r0 * 128 + ((slot ^ (r0 & 31)) << 2)) = a;
            *(float4*)(vbuf + r1 * 128 + ((slot ^ (r1 & 31)) << 2)) = c;
        }
    }
    __syncthreads();

    // ---- coalesced store vbuf -> vdst ----
#pragma unroll
    for (int j = 0; j < 8; ++j) {
        int i  = j * 16 + rl;
        int gp = base + (i >> 6) * h_off + (i & 63) * rstride;
        ((float4*)vdst)[gp * 32 + c4] =
            *(const float4*)(vbuf + i * 128 + (((c4 ^ (i & 31)) << 2)));
    }
}

extern "C" void kernel_launch(void* const* d_in, const int* in_sizes, int n_in,
                              void* d_out, int out_size, void* d_ws, size_t ws_size,
                              hipStream_t stream) {
    const float* x   = (const float*)d_in[0];
    const float* qkw = (const float*)d_in[1];
    float* out = (float*)d_out;
    unsigned short* PT = (unsigned short*)d_ws;   // 13*16384 bf16 = 416 KB
    float* dwt = (float*)((char*)d_ws + WS_DWT_OFF);

    (void)hipFuncSetAttribute((const void*)prep_kernel,
                              hipFuncAttributeMaxDynamicSharedMemorySize, PREP_LDS);

    prep_kernel<<<13, 512, PREP_LDS, stream>>>(qkw, PT);

    if (ws_size >= (size_t)WS_NEED4) {
        (void)hipFuncSetAttribute((const void*)weights4_kernel<7>,
                                  hipFuncAttributeMaxDynamicSharedMemorySize, LDS_W4);
        (void)hipFuncSetAttribute((const void*)weights4_kernel<6>,
                                  hipFuncAttributeMaxDynamicSharedMemorySize, LDS_W4);
        (void)hipFuncSetAttribute((const void*)mix_kernel<7,4>,
                                  hipFuncAttributeMaxDynamicSharedMemorySize, LDS_MIX);
        (void)hipFuncSetAttribute((const void*)mix_kernel<6,4>,
                                  hipFuncAttributeMaxDynamicSharedMemorySize, LDS_MIX);

        weights4_kernel<7><<<1024, 512, LDS_W4, stream>>>(
            x, PT, dwt, /*s0=*/0, /*base_mul=*/128, /*h_off=*/64, /*rstride=*/1);
        mix_kernel<7,4><<<1024, 512, LDS_MIX, stream>>>(
            x, out, dwt, /*s0=*/0, /*base_mul=*/128, /*h_off=*/64, /*rstride=*/1);
        weights4_kernel<6><<<1024, 512, LDS_W4, stream>>>(
            x, PT, dwt, /*s0=*/7, /*base_mul=*/2, /*h_off=*/1, /*rstride=*/128);
        mix_kernel<6,4><<<1024, 512, LDS_MIX, stream>>>(
            out, out, dwt, /*s0=*/7, /*base_mul=*/2, /*h_off=*/1, /*rstride=*/128);
    } else {
        // tier-2: r5-verified weights2 (dwt 6.8MB) + mix<NPART=2>
        (void)hipFuncSetAttribute((const void*)weights2_kernel<7>,
                                  hipFuncAttributeMaxDynamicSharedMemorySize, LDS_W2);
        (void)hipFuncSetAttribute((const void*)weights2_kernel<6>,
                                  hipFuncAttributeMaxDynamicSharedMemorySize, LDS_W2);
        (void)hipFuncSetAttribute((const void*)mix_kernel<7,2>,
                                  hipFuncAttributeMaxDynamicSharedMemorySize, LDS_MIX);
        (void)hipFuncSetAttribute((const void*)mix_kernel<6,2>,
                                  hipFuncAttributeMaxDynamicSharedMemorySize, LDS_MIX);

        weights2_kernel<7><<<1024, 512, LDS_W2, stream>>>(
            x, PT, dwt, 0, 128, 64, 1);
        mix_kernel<7,2><<<1024, 512, LDS_MIX, stream>>>(
            x, out, dwt, 0, 128, 64, 1);
        weights2_kernel<6><<<1024, 512, LDS_W2, stream>>>(
            x, PT, dwt, 7, 2, 1, 128);
        mix_kernel<6,2><<<1024, 512, LDS_MIX, stream>>>(
            out, out, dwt, 7, 2, 1, 128);
    }
}

// Round 9
// 197.273 us; speedup vs baseline: 1.6577x; 1.0440x over previous
//
#include <hip/hip_runtime.h>
#include <hip/hip_bf16.h>

// ---------------------------------------------------------------------------
// FFT butterfly attention. delta = x_a^T P (x_a - x_b), P = scale*Wq*Wk^T
// (bf16, MFMA prep). w0 = sigmoid(delta); v' = mix(va, vb).
//
// Split design (r5-r8 verified): weights depend only on x/PT, never v.
//  * weights_all_kernel (NEW r9): BOTH halves in ONE 2048-block dispatch
//    (halves independent: both read only x/PT). Per-block body = r8's
//    verified weights4 (2x2 wave tiling, XOR-swizzled xb, 4 partials) plus
//    PT DOUBLE-BUFFER PREFETCH: stage u+1's 8 A-frag loads issue at the top
//    of stage u and drain under 16 MFMAs + ~130-op dot (~340cyc > L2 lat).
//    r8 counters: VALUBusy 36 / MfmaUtil 14 / low occupancy = latency-bound
//    on the per-stage PT->MFMA serial L2 stall; this removes it.
//  * mix_kernel (r8, verified): global distribute (L3 absorbs scatter),
//    register butterfly, LDS-staged swizzled coalesced store. 1 barrier.
//  * tier-2 fallback (ws < 14.2MB): r5-verified weights2 + mix<NPART=2>.
//
// v register layout (pair-local): at stage u, lane L holds BOTH partners:
//   vlo = row ((L>>u)<<(u+1)) | (L & (2^u-1)),  vhi = vlo + 2^u
// (pair index of lane L == L; exchange partner lane L^2^u.)
// ---------------------------------------------------------------------------

typedef __bf16 bf16x8 __attribute__((ext_vector_type(8)));
typedef float  f32x4  __attribute__((ext_vector_type(4)));

#define XSTR 136                    // bf16/row, UNswizzled xb (prep + weights2)
#define XB_BYTES  (128 * XSTR * 2)  // 34816
#define PREP_LDS  (2 * XB_BYTES)    // 69632
#define LDS_W2    XB_BYTES          // weights2: unswizzled xb

#define XW 128                      // bf16/row, swizzled xb (weights_all)
#define LDS_W4    (128 * XW * 2)    // 32768

#define LDS_MIX   (128 * 128 * 4)   // 65536 (vbuf, swizzled)

// workspace layout
#define WS_DWT_OFF (512 * 1024)                      // PT in [0, 416K)
#define DWT4_BYTES (13 * 1024 * 4 * 64 * 4)          // 13.6 MB
#define WS_NEED4   (WS_DWT_OFF + DWT4_BYTES)

__device__ __forceinline__ float ubits(unsigned int u) {
    union { unsigned int u; float f; } v; v.u = u; return v.f;
}
__device__ __forceinline__ unsigned short f2bf(float f) {
    union { float f; unsigned int u; } v; v.f = f;
    unsigned int u = v.u;
    return (unsigned short)((u + 0x7fffu + ((u >> 16) & 1u)) >> 16);
}
__device__ __forceinline__ int swzr(int r) { return ((r >> 1) ^ (r >> 2)) & 15; }

#define DPP_MOV_F(x, ctrl) \
    __int_as_float(__builtin_amdgcn_update_dpp(0, __float_as_int(x), (ctrl), 0xF, 0xF, true))

// cross-lane xor exchange with lane ^ (1<<u); u is compile-time-folded
__device__ __forceinline__ float xlane_u(float x, int u, int lane) {
    if (u == 0) return DPP_MOV_F(x, 0xB1);   // quad_perm xor1
    if (u == 1) return DPP_MOV_F(x, 0x4E);   // quad_perm xor2
    if (u == 2) return __int_as_float(__builtin_amdgcn_ds_swizzle(__float_as_int(x), 0x101F)); // xor4
    if (u == 3) return __int_as_float(__builtin_amdgcn_ds_swizzle(__float_as_int(x), 0x201F)); // xor8
    if (u == 4) return __int_as_float(__builtin_amdgcn_ds_swizzle(__float_as_int(x), 0x401F)); // xor16
    return __int_as_float(__builtin_amdgcn_ds_bpermute((lane ^ 32) << 2, __float_as_int(x))); // xor32
}

// ---------------- prep: PTf = fragment-major P^T -----------------------------
// frag (ci,kk) of 16-row tile ci at uint4 Pf[(ci*4+kk)*64 + lane]: 1KB coalesced.
__global__ __launch_bounds__(512)
void prep_kernel(const float* __restrict__ qkw, unsigned short* __restrict__ PT) {
    extern __shared__ char smem[];
    unsigned short* wkb = (unsigned short*)smem;              // A: Wk rows (n)
    unsigned short* wqb = (unsigned short*)(smem + XB_BYTES); // B: Wq rows (k)
    const int s = blockIdx.x;
    const float* Wq = qkw + (size_t)s * 32768;
    const float* Wk = Wq + 16384;
    const int tid = threadIdx.x;
    const int rl = tid >> 5, c4 = tid & 31;
#pragma unroll
    for (int j = 0; j < 8; ++j) {
        int r = j * 16 + rl;
        float4 vq = ((const float4*)Wq)[r * 32 + c4];
        float4 vk = ((const float4*)Wk)[r * 32 + c4];
        ushort4 uq; uq.x = f2bf(vq.x); uq.y = f2bf(vq.y); uq.z = f2bf(vq.z); uq.w = f2bf(vq.w);
        ushort4 uk; uk.x = f2bf(vk.x); uk.y = f2bf(vk.y); uk.z = f2bf(vk.z); uk.w = f2bf(vk.w);
        *(ushort4*)(wqb + r * XSTR + c4 * 4) = uq;
        *(ushort4*)(wkb + r * XSTR + c4 * 4) = uk;
    }
    __syncthreads();
    const int lane = tid & 63, w = tid >> 6;
    const int lane15 = lane & 15, quad = lane >> 4;
    f32x4 acc[8] = {};
#pragma unroll
    for (int kk = 0; kk < 4; ++kk) {
        bf16x8 a = *(const bf16x8*)(wkb + (w * 16 + lane15) * XSTR + kk * 32 + quad * 8);
#pragma unroll
        for (int ct = 0; ct < 8; ++ct) {
            bf16x8 b = *(const bf16x8*)(wqb + (ct * 16 + lane15) * XSTR + kk * 32 + quad * 8);
            acc[ct] = __builtin_amdgcn_mfma_f32_16x16x32_bf16(a, b, acc[ct], 0, 0, 0);
        }
    }
    // acc[ct][r] = PT[n][k], n = w*16 + quad*4 + r, k = ct*16 + lane15
    unsigned short* dst = PT + s * 16384;
#pragma unroll
    for (int ct = 0; ct < 8; ++ct) {
        const int kkf = ct >> 1;
        const int qf  = (ct & 1) * 2 + (lane15 >> 3);
        const int e   = lane15 & 7;
#pragma unroll
        for (int r = 0; r < 4; ++r) {
            int fi = (w * 4 + kkf) * 64 + qf * 16 + quad * 4 + r;
            dst[fi * 8 + e] = f2bf(acc[ct][r] * 0.17677669529663687f);
        }
    }
}

// ---------------- staging helpers -------------------------------------------
__device__ __forceinline__ void stage_xb(unsigned short* xb, const float* xsrc,
                                         int tid, int base, int h_off, int rstride) {
    const int rl = tid >> 5, c4 = tid & 31;
#pragma unroll
    for (int j = 0; j < 8; ++j) {
        int i  = j * 16 + rl;
        int gp = base + (i >> 6) * h_off + (i & 63) * rstride;
        float4 val = ((const float4*)xsrc)[gp * 32 + c4];
        ushort4 us; us.x = f2bf(val.x); us.y = f2bf(val.y);
        us.z = f2bf(val.z); us.w = f2bf(val.w);
        *(ushort4*)(xb + i * XSTR + c4 * 4) = us;
    }
}

// swizzled: row i, 16B slot s lives at byte i*256 + ((s ^ swzr(i))*16)
__device__ __forceinline__ void stage_xb_swz(unsigned short* xb, const float* xsrc,
                                             int tid, int base, int h_off, int rstride) {
    const int rl = tid >> 5, c4 = tid & 31;
#pragma unroll
    for (int j = 0; j < 8; ++j) {
        int i  = j * 16 + rl;
        int gp = base + (i >> 6) * h_off + (i & 63) * rstride;
        float4 val = ((const float4*)xsrc)[gp * 32 + c4];
        ushort4 us; us.x = f2bf(val.x); us.y = f2bf(val.y);
        us.z = f2bf(val.z); us.w = f2bf(val.w);
        int slot = c4 >> 1, half = c4 & 1;
        *(ushort4*)(xb + i * XW + (((slot ^ swzr(i)) << 3) + half * 4)) = us;
    }
}

// ---------------- weights body: 2x2 tiling, swizzled xb, PT dbuf prefetch ----
template<int NS>
__device__ __forceinline__ void weights_body(const float* __restrict__ xsrc,
                                             const unsigned short* __restrict__ PT,
                                             float* __restrict__ dwt,
                                             unsigned short* xb, int tid, int bid,
                                             int s0, int base_mul, int h_off, int rstride)
{
    const int b    = bid >> 6;
    const int sub  = bid & 63;
    const int base = b * 8192 + sub * base_mul;

    stage_xb_swz(xb, xsrc, tid, base, h_off, rstride);

    const int lane = tid & 63, w = tid >> 6;
    const int lane15 = lane & 15, quad = lane >> 4;
    const int dh = w >> 1;            // dim-slice: dims dh*32..+31
    const int ph = w & 1;             // pair-slice: pairs ph*32..+31

    // ---- prologue: prefetch stage-0 A-frags (overlaps staging-wait) ----
    uint4 af[2][2][4];
    {
        const uint4* Pf = (const uint4*)PT + (size_t)s0 * 2048;
#pragma unroll
        for (int mt = 0; mt < 2; ++mt)
#pragma unroll
            for (int kk = 0; kk < 4; ++kk)
                af[0][mt][kk] = Pf[((dh * 2 + mt) * 4 + kk) * 64 + lane];
    }
    __syncthreads();   // xb ready; NO further barriers (xb read-only below)

#pragma unroll
    for (int u = 0; u < NS; ++u) {
        const int cur = u & 1, nxt = cur ^ 1;   // compile-time (full unroll)
        const int t   = 1 << u;
        const int tm1 = t - 1;

        // ---- prefetch next stage's A-frags; drain under MFMA + dot ----
        if (u + 1 < NS) {
            const uint4* Pf = (const uint4*)PT + (size_t)(s0 + u + 1) * 2048;
#pragma unroll
            for (int mt = 0; mt < 2; ++mt)
#pragma unroll
                for (int kk = 0; kk < 4; ++kk)
                    af[nxt][mt][kk] = Pf[((dh * 2 + mt) * 4 + kk) * 64 + lane];
        }

        // ---- Gt subtile: dims dh*32..+31 (C rows), pairs ph*32..+31 (C cols)
        f32x4 acc[2][2] = {};
#pragma unroll
        for (int pg = 0; pg < 2; ++pg) {
            const int p  = (ph * 2 + pg) * 16 + lane15;
            const int ar = ((p & ~tm1) << 1) | (p & tm1);
            const int swa = swzr(ar);
            const unsigned short* brow = xb + ar * XW;
#pragma unroll
            for (int kk = 0; kk < 4; ++kk) {
                bf16x8 bfrag = *(const bf16x8*)(brow + (((kk * 4 + quad) ^ swa) << 3));
#pragma unroll
                for (int mt = 0; mt < 2; ++mt) {
                    union { uint4 u; bf16x8 b; } av; av.u = af[cur][mt][kk];
                    acc[mt][pg] = __builtin_amdgcn_mfma_f32_16x16x32_bf16(av.b, bfrag, acc[mt][pg], 0, 0, 0);
                }
            }
        }

        // ---- partial dot over dims dh*32..+31; quad-reduce xor16+xor32 ----
        float sm[2];
#pragma unroll
        for (int pg = 0; pg < 2; ++pg) {
            const int p  = (ph * 2 + pg) * 16 + lane15;
            const int ar = ((p & ~tm1) << 1) | (p & tm1);
            const int br = ar + t;
            const int swa = swzr(ar), swb = swzr(br);
            float s = 0.f;
#pragma unroll
            for (int mt = 0; mt < 2; ++mt) {
                const int slot = dh * 4 + mt * 2 + (quad >> 1);
                uint2 ua = *(const uint2*)(xb + ar * XW + (((slot ^ swa) << 3) + (quad & 1) * 4));
                uint2 ub = *(const uint2*)(xb + br * XW + (((slot ^ swb) << 3) + (quad & 1) * 4));
                float a0 = ubits(ua.x << 16), a1 = ubits(ua.x & 0xffff0000u);
                float a2 = ubits(ua.y << 16), a3 = ubits(ua.y & 0xffff0000u);
                float b0 = ubits(ub.x << 16), b1 = ubits(ub.x & 0xffff0000u);
                float b2 = ubits(ub.y << 16), b3 = ubits(ub.y & 0xffff0000u);
                s += acc[mt][pg][0] * (a0 - b0) + acc[mt][pg][1] * (a1 - b1)
                   + acc[mt][pg][2] * (a2 - b2) + acc[mt][pg][3] * (a3 - b3);
            }
            s += xlane_u(s, 4, lane);
            s += xlane_u(s, 5, lane);
            sm[pg] = s;
        }
        // lanes 0..31 store pairs ph*32 + (lane&31), partial dh (coalesced 128B)
        float v = (lane & 16) ? sm[1] : sm[0];
        if (lane < 32)
            dwt[(((size_t)(s0 + u) * 1024 + bid) * 4 + dh) * 64 + ph * 32 + (lane & 31)] = v;
    }
}

// one dispatch, both halves (independent: both read only x/PT)
__global__ __launch_bounds__(512, 4)
void weights_all_kernel(const float* __restrict__ xsrc,
                        const unsigned short* __restrict__ PT,
                        float* __restrict__ dwt)
{
    extern __shared__ char smem[];
    unsigned short* xb = (unsigned short*)smem;   // swizzled [128][XW]
    const int tid = threadIdx.x;
    if (blockIdx.x < 1024) {
        weights_body<7>(xsrc, PT, dwt, xb, tid, blockIdx.x,
                        /*s0=*/0, /*base_mul=*/128, /*h_off=*/64, /*rstride=*/1);
    } else {
        weights_body<6>(xsrc, PT, dwt, xb, tid, blockIdx.x - 1024,
                        /*s0=*/7, /*base_mul=*/2, /*h_off=*/1, /*rstride=*/128);
    }
}

// ---------------- weights2: r5-verified fallback (2 partials) ----------------
template<int NS>
__global__ __launch_bounds__(512, 4)
void weights2_kernel(const float* __restrict__ xsrc,
                     const unsigned short* __restrict__ PT,
                     float* __restrict__ dwt,
                     int s0, int base_mul, int h_off, int rstride)
{
    extern __shared__ char smem[];
    unsigned short* xb = (unsigned short*)smem;

    const int tid  = threadIdx.x;
    const int b    = blockIdx.x >> 6;
    const int sub  = blockIdx.x & 63;
    const int base = b * 8192 + sub * base_mul;

    stage_xb(xb, xsrc, tid, base, h_off, rstride);

    const int lane = tid & 63, w = tid >> 6;
    const int lane15 = lane & 15, quad = lane >> 4;
    const int nt = w & 3;
    const int mh = w >> 2;
    const int p  = nt * 16 + lane15;

    __syncthreads();

#pragma unroll
    for (int u = 0; u < NS; ++u) {
        const int t   = 1 << u;
        const int tm1 = t - 1;
        const int ar  = ((p & ~tm1) << 1) | (p & tm1);

        float sm = 0.f;
        {
            const uint4* Pf = (const uint4*)PT + (size_t)(s0 + u) * 2048;
            const unsigned short* brow = xb + ar * XSTR + quad * 8;
            f32x4 acc[4] = {};
#pragma unroll
            for (int kk = 0; kk < 4; ++kk) {
                bf16x8 bfrag = *(const bf16x8*)(brow + kk * 32);
#pragma unroll
                for (int mt = 0; mt < 4; ++mt) {
                    union { uint4 u; bf16x8 b; } av;
                    av.u = Pf[((mh * 4 + mt) * 4 + kk) * 64 + lane];
                    acc[mt] = __builtin_amdgcn_mfma_f32_16x16x32_bf16(av.b, bfrag, acc[mt], 0, 0, 0);
                }
            }
            const unsigned short* da = xb + ar * XSTR + mh * 64 + quad * 4;
            const unsigned short* db = da + t * XSTR;
#pragma unroll
            for (int mt = 0; mt < 4; ++mt) {
                uint2 ua = *(const uint2*)(da + mt * 16);
                uint2 ub = *(const uint2*)(db + mt * 16);
                float a0 = ubits(ua.x << 16), a1 = ubits(ua.x & 0xffff0000u);
                float a2 = ubits(ua.y << 16), a3 = ubits(ua.y & 0xffff0000u);
                float b0 = ubits(ub.x << 16), b1 = ubits(ub.x & 0xffff0000u);
                float b2 = ubits(ub.y << 16), b3 = ubits(ub.y & 0xffff0000u);
                sm += acc[mt][0] * (a0 - b0) + acc[mt][1] * (a1 - b1)
                    + acc[mt][2] * (a2 - b2) + acc[mt][3] * (a3 - b3);
            }
        }
        sm += xlane_u(sm, 4, lane);
        sm += xlane_u(sm, 5, lane);
        if (lane < 16)
            dwt[((size_t)(s0 + u) * 1024 + blockIdx.x) * 128 + mh * 64 + nt * 16 + lane] = sm;
    }
}

// ---------------- mix: global distribute, LDS-staged coalesced store ---------
template<int NS, int NPART>
__global__ __launch_bounds__(512, 4)
void mix_kernel(const float* __restrict__ vsrc,
                float* __restrict__ vdst,
                const float* __restrict__ dwt,
                int s0, int base_mul, int h_off, int rstride)
{
    extern __shared__ char smem[];
    float* vbuf = (float*)smem;   // [128][128], 16B slots XOR'd by (row&31)

    const int tid  = threadIdx.x;
    const int b    = blockIdx.x >> 6;
    const int sub  = blockIdx.x & 63;
    const int base = b * 8192 + sub * base_mul;
    const int lane = tid & 63, w = tid >> 6;
    const int rl = tid >> 5, c4 = tid & 31;

    // ---- distribute directly from global (r5-verified path; L3 absorbs) ----
    float vlo[16], vhi[16];
    {
        int r0 = 2 * lane, r1 = r0 + 1;
        int gp0 = base + (r0 >> 6) * h_off + (r0 & 63) * rstride;
        int gp1 = base + (r1 >> 6) * h_off + (r1 & 63) * rstride;
        const float* p0 = vsrc + (size_t)gp0 * 128 + w * 16;
        const float* p1 = vsrc + (size_t)gp1 * 128 + w * 16;
#pragma unroll
        for (int j = 0; j < 4; ++j) {
            float4 a = ((const float4*)p0)[j];
            float4 c = ((const float4*)p1)[j];
            vlo[4*j] = a.x; vlo[4*j+1] = a.y; vlo[4*j+2] = a.z; vlo[4*j+3] = a.w;
            vhi[4*j] = c.x; vhi[4*j+1] = c.y; vhi[4*j+2] = c.z; vhi[4*j+3] = c.w;
        }
    }

#pragma unroll
    for (int u = 0; u < NS; ++u) {
        const float* dw = dwt + ((size_t)(s0 + u) * 1024 + blockIdx.x) * (NPART * 64);
        float d = 0.f;
#pragma unroll
        for (int k = 0; k < NPART; ++k) d += dw[k * 64 + lane];
        const float w0 = 1.0f / (1.0f + __expf(-d));
        if (u < NS - 1) {
            const bool isE = ((lane >> u) & 1) == 0;
            const float wk = isE ? w0 : 1.0f - w0;
#pragma unroll
            for (int j = 0; j < 16; ++j) {
                float a = vlo[j], c = vhi[j];
                float s    = a + c;
                float keep = c + wk * (a - c);   // E: out_a ; O: out_b
                float send = s - keep;           // E: out_b ; O: out_a
                float ex   = xlane_u(send, u, lane);
                vlo[j] = isE ? keep : ex;
                vhi[j] = isE ? ex : keep;
            }
        } else {
            const float w1 = 1.0f - w0;
#pragma unroll
            for (int j = 0; j < 16; ++j) {
                float a = vlo[j], c = vhi[j];
                float oa = w0 * a + w1 * c;
                vlo[j] = oa;
                vhi[j] = a + c - oa;
            }
        }
    }

    // ---- write registers to swizzled vbuf (final-stage layout) ----
    {
        const int FU = NS - 1;
        int r0 = ((lane >> FU) << (FU + 1)) | (lane & ((1 << FU) - 1));
        int r1 = r0 + (1 << FU);
#pragma unroll
        for (int j = 0; j < 4; ++j) {
            float4 a; a.x = vlo[4*j]; a.y = vlo[4*j+1]; a.z = vlo[4*j+2]; a.w = vlo[4*j+3];
            float4 c; c.x = vhi[4*j]; c.y = vhi[4*j+1]; c.z = vhi[4*j+2]; c.w = vhi[4*j+3];
            int slot = w * 4 + j;
            *(float4*)(vbuf + r0 * 128 + ((slot ^ (r0 & 31)) << 2)) = a;
            *(float4*)(vbuf + r1 * 128 + ((slot ^ (r1 & 31)) << 2)) = c;
        }
    }
    __syncthreads();

    // ---- coalesced store vbuf -> vdst ----
#pragma unroll
    for (int j = 0; j < 8; ++j) {
        int i  = j * 16 + rl;
        int gp = base + (i >> 6) * h_off + (i & 63) * rstride;
        ((float4*)vdst)[gp * 32 + c4] =
            *(const float4*)(vbuf + i * 128 + (((c4 ^ (i & 31)) << 2)));
    }
}

extern "C" void kernel_launch(void* const* d_in, const int* in_sizes, int n_in,
                              void* d_out, int out_size, void* d_ws, size_t ws_size,
                              hipStream_t stream) {
    const float* x   = (const float*)d_in[0];
    const float* qkw = (const float*)d_in[1];
    float* out = (float*)d_out;
    unsigned short* PT = (unsigned short*)d_ws;   // 13*16384 bf16 = 416 KB
    float* dwt = (float*)((char*)d_ws + WS_DWT_OFF);

    (void)hipFuncSetAttribute((const void*)prep_kernel,
                              hipFuncAttributeMaxDynamicSharedMemorySize, PREP_LDS);

    prep_kernel<<<13, 512, PREP_LDS, stream>>>(qkw, PT);

    if (ws_size >= (size_t)WS_NEED4) {
        (void)hipFuncSetAttribute((const void*)weights_all_kernel,
                                  hipFuncAttributeMaxDynamicSharedMemorySize, LDS_W4);
        (void)hipFuncSetAttribute((const void*)mix_kernel<7,4>,
                                  hipFuncAttributeMaxDynamicSharedMemorySize, LDS_MIX);
        (void)hipFuncSetAttribute((const void*)mix_kernel<6,4>,
                                  hipFuncAttributeMaxDynamicSharedMemorySize, LDS_MIX);

        // both weights halves in one dispatch (independent of mix chain)
        weights_all_kernel<<<2048, 512, LDS_W4, stream>>>(x, PT, dwt);

        // stages 0..6: contiguous 128-position blocks
        mix_kernel<7,4><<<1024, 512, LDS_MIX, stream>>>(
            x, out, dwt, /*s0=*/0, /*base_mul=*/128, /*h_off=*/64, /*rstride=*/1);
        // stages 7..12: 2 lo x 64 hi (stride 128); in-place on d_out
        mix_kernel<6,4><<<1024, 512, LDS_MIX, stream>>>(
            out, out, dwt, /*s0=*/7, /*base_mul=*/2, /*h_off=*/1, /*rstride=*/128);
    } else {
        // tier-2: r5-verified weights2 (dwt 6.8MB) + mix<NPART=2>
        (void)hipFuncSetAttribute((const void*)weights2_kernel<7>,
                                  hipFuncAttributeMaxDynamicSharedMemorySize, LDS_W2);
        (void)hipFuncSetAttribute((const void*)weights2_kernel<6>,
                                  hipFuncAttributeMaxDynamicSharedMemorySize, LDS_W2);
        (void)hipFuncSetAttribute((const void*)mix_kernel<7,2>,
                                  hipFuncAttributeMaxDynamicSharedMemorySize, LDS_MIX);
        (void)hipFuncSetAttribute((const void*)mix_kernel<6,2>,
                                  hipFuncAttributeMaxDynamicSharedMemorySize, LDS_MIX);

        weights2_kernel<7><<<1024, 512, LDS_W2, stream>>>(
            x, PT, dwt, 0, 128, 64, 1);
        mix_kernel<7,2><<<1024, 512, LDS_MIX, stream>>>(
            x, out, dwt, 0, 128, 64, 1);
        weights2_kernel<6><<<1024, 512, LDS_W2, stream>>>(
            x, PT, dwt, 7, 2, 1, 128);
        mix_kernel<6,2><<<1024, 512, LDS_MIX, stream>>>(
            out, out, dwt, 7, 2, 1, 128);
    }
}